// Round 8
// baseline (1283.602 us; speedup 1.0000x reference)
//
#include <hip/hip_runtime.h>
#include <math.h>

#define NATOMS 16384
#define NEDGES 524288
#define NLAYERS 4
#define TE 64      // edges per block in msg kernel

typedef __bf16 bf16x8 __attribute__((ext_vector_type(8)));
typedef __bf16 bf16x4 __attribute__((ext_vector_type(4)));
typedef __bf16 bf16x2 __attribute__((ext_vector_type(2)));
typedef float f32x4 __attribute__((ext_vector_type(4)));

// fast silu: x * rcp(1+exp(-x))
__device__ __forceinline__ float silu_f(float x) {
  return x * __builtin_amdgcn_rcpf(1.0f + __expf(-x));
}

// ---------------- CSR preprocessing ----------------
__global__ __launch_bounds__(1024) void scan_kernel(
    const int* __restrict__ counts, int* __restrict__ cursor,
    float* __restrict__ degf)
{
  __shared__ int s_tot[1024];
  int tid = threadIdx.x;
  int v[16];
  {
    const int4* cp = (const int4*)(counts + tid * 16);
    int4 a = cp[0], b = cp[1], c = cp[2], d = cp[3];
    v[0]=a.x; v[1]=a.y; v[2]=a.z; v[3]=a.w;
    v[4]=b.x; v[5]=b.y; v[6]=b.z; v[7]=b.w;
    v[8]=c.x; v[9]=c.y; v[10]=c.z; v[11]=c.w;
    v[12]=d.x; v[13]=d.y; v[14]=d.z; v[15]=d.w;
  }
  int tot = 0;
  #pragma unroll
  for (int i = 0; i < 16; i++) tot += v[i];
  s_tot[tid] = tot;
  __syncthreads();
  for (int off = 1; off < 1024; off <<= 1) {
    int t = (tid >= off) ? s_tot[tid - off] : 0;
    __syncthreads();
    s_tot[tid] += t;
    __syncthreads();
  }
  int run = s_tot[tid] - tot;   // exclusive prefix
  #pragma unroll
  for (int i = 0; i < 16; i++) {
    cursor[tid * 16 + i] = run;
    degf[tid * 16 + i] = (float)v[i];
    run += v[i];
  }
}

// scatter + RBF fused: each edge computes its sorted slot p, writes esrc/edst
// AND its RBF features directly to efb[p].
__global__ __launch_bounds__(256) void scatter_rbf_kernel(
    const int* __restrict__ src, const int* __restrict__ dst,
    int* __restrict__ cursor, const float* __restrict__ pos,
    int* __restrict__ esrc, int* __restrict__ edst,
    __bf16* __restrict__ efb)
{
  int e = blockIdx.x * 256 + threadIdx.x;
  int s = src[e], d = dst[e];
  int p = atomicAdd(&cursor[d], 1);
  esrc[p] = s;
  edst[p] = d;
  float dx = pos[d * 3 + 0] - pos[s * 3 + 0];
  float dy = pos[d * 3 + 1] - pos[s * 3 + 1];
  float dz = pos[d * 3 + 2] - pos[s * 3 + 2];
  float dist = sqrtf(dx * dx + dy * dy + dz * dz + 1e-12f);
  float env = (dist < 10.0f)
                  ? 0.5f * (cosf(3.14159265358979f * dist * 0.1f) + 1.0f)
                  : 0.0f;
  bf16x8 o0, o1;
  #pragma unroll
  for (int i = 0; i < 16; i++) {
    float c = (10.0f / 15.0f) * (float)i;
    float t = dist - c;
    float v = env * __expf(-t * t * 1.28f);
    if (i < 8) o0[i] = (__bf16)v; else o1[i - 8] = (__bf16)v;
  }
  *(bf16x8*)(efb + (size_t)p * 16 + 0) = o0;
  *(bf16x8*)(efb + (size_t)p * 16 + 8) = o1;
}

// ---------------- merged front kernel v2 ----------------
// prep: LDS-tiled 64x64 transposes (coalesced both sides),
// 16-row-slab fusion GEMM (16-way ILP), 32-node embed blocks.
#define NB_PL   50
#define NB_PREP (NB_PL * NLAYERS)
#define NB_HIST (NEDGES / 256)
#define NB_EMB  (NATOMS / 32)

__global__ __launch_bounds__(256) void front_kernel(
    const float* __restrict__ mW1, const float* __restrict__ mW2,
    const float* __restrict__ uW1, const float* __restrict__ uW2,
    const float* __restrict__ mb2,
    __bf16* __restrict__ W1at, __bf16* __restrict__ W1bt,
    __bf16* __restrict__ B2c, __bf16* __restrict__ uW1ft,
    __bf16* __restrict__ uW2t, float* __restrict__ b2u,
    const int* __restrict__ dstI, int* __restrict__ counts,
    const float* __restrict__ x, const float* __restrict__ eW1,
    const float* __restrict__ eb1, const float* __restrict__ eW2,
    const float* __restrict__ eb2, float* __restrict__ h,
    __bf16* __restrict__ hb)
{
  __shared__ __align__(16) char smem[19712];
  int bxf = blockIdx.x, tid = threadIdx.x;

  if (bxf < NB_PREP) {
    int l = bxf / NB_PL;
    int bx = bxf - l * NB_PL;
    if (bx < 16) {
      // W1at / W1bt: transpose 64x64 tiles of mW1 rows [0,256)
      float (*tile)[65] = (float(*)[65])smem;
      int tt = bx & 7;
      int row0 = ((tt >> 2) * 64) + ((bx < 8) ? 0 : 128);   // source k-row
      int col0 = (tt & 3) * 64;                             // source col (c)
      const float* Sp = mW1 + (size_t)l * (272 * 256) + (size_t)row0 * 256 + col0;
      __bf16* Dq = ((bx < 8) ? W1at : W1bt) + (size_t)l * (256 * 128);
      int dro = (bx < 8) ? row0 : row0 - 128;
      int c = tid & 63, r4 = tid >> 6;
      #pragma unroll
      for (int i = 0; i < 16; i++)
        tile[r4 + i * 4][c] = Sp[(size_t)(r4 + i * 4) * 256 + c];
      __syncthreads();
      #pragma unroll
      for (int i = 0; i < 16; i++) {
        int dr = r4 + i * 4;
        Dq[(size_t)(col0 + dr) * 128 + dro + c] = (__bf16)tile[c][dr];
      }
    } else if (bx == 16) {
      // B2c: rows 256..271 of mW1 -> [c][k] with zero pad to k=32
      float (*t3)[257] = (float(*)[257])smem;
      const float* Sp = mW1 + (size_t)l * (272 * 256) + 256 * 256;
      #pragma unroll
      for (int i = 0; i < 16; i++) t3[i][tid] = Sp[i * 256 + tid];
      __syncthreads();
      __bf16* Dp = B2c + (size_t)l * (256 * 32) + (size_t)tid * 32;
      #pragma unroll
      for (int g = 0; g < 4; g++) {
        bf16x8 o;
        #pragma unroll
        for (int j2 = 0; j2 < 8; j2++) {
          int k = g * 8 + j2;
          o[j2] = (__bf16)((k < 16) ? t3[k][tid] : 0.0f);
        }
        *(bf16x8*)(Dp + g * 8) = o;
      }
    } else if (bx < 25) {
      // uW1ft copy part (k<128): transpose 64x64 tiles of uW1
      float (*tile)[65] = (float(*)[65])smem;
      int tt = bx - 17;
      int row0 = (tt >> 2) * 64;         // k
      int col0 = (tt & 3) * 64;          // n
      const float* Sp = uW1 + (size_t)l * 65536 + (size_t)row0 * 256 + col0;
      __bf16* Dq = uW1ft + (size_t)l * (256 * 384);
      int c = tid & 63, r4 = tid >> 6;
      #pragma unroll
      for (int i = 0; i < 16; i++)
        tile[r4 + i * 4][c] = Sp[(size_t)(r4 + i * 4) * 256 + c];
      __syncthreads();
      #pragma unroll
      for (int i = 0; i < 16; i++) {
        int dr = r4 + i * 4;
        Dq[(size_t)(col0 + dr) * 384 + row0 + c] = (__bf16)tile[c][dr];
      }
    } else if (bx < 41) {
      // fusion slab: F[r0+r][n] = sum_j mW2[r0+r][j] * uW1[128+j][n]
      float (*sA)[128] = (float(*)[128])smem;
      int r0 = (bx - 25) * 16;
      const float* Ap = mW2 + (size_t)(l * 256 + r0) * 128;
      #pragma unroll
      for (int i = 0; i < 8; i++) {
        int idx = i * 256 + tid;
        ((float*)smem)[idx] = Ap[idx];
      }
      __syncthreads();
      const float* Bp = uW1 + (size_t)l * 65536 + 128 * 256 + tid;
      float acc[16];
      #pragma unroll
      for (int r = 0; r < 16; r++) acc[r] = 0.0f;
      for (int k = 0; k < 128; k++) {
        float b = Bp[(size_t)k * 256];
        #pragma unroll
        for (int r = 0; r < 16; r++) acc[r] += sA[r][k] * b;
      }
      __bf16* Dp = uW1ft + (size_t)l * (256 * 384) + (size_t)tid * 384 + 128 + r0;
      bf16x8 o0, o1;
      #pragma unroll
      for (int r = 0; r < 8; r++) { o0[r] = (__bf16)acc[r]; o1[r] = (__bf16)acc[8 + r]; }
      *(bf16x8*)Dp = o0;
      *(bf16x8*)(Dp + 8) = o1;
    } else if (bx < 49) {
      // uW2t: transpose 64x64 tiles of uW2 (256x128)
      float (*tile)[65] = (float(*)[65])smem;
      int tt = bx - 41;
      int row0 = (tt >> 1) * 64;     // k in [0,256)
      int col0 = (tt & 1) * 64;      // n in [0,128)
      const float* Sp = uW2 + (size_t)l * (256 * 128) + (size_t)row0 * 128 + col0;
      __bf16* Dq = uW2t + (size_t)l * (128 * 256);
      int c = tid & 63, r4 = tid >> 6;
      #pragma unroll
      for (int i = 0; i < 16; i++)
        tile[r4 + i * 4][c] = Sp[(size_t)(r4 + i * 4) * 128 + c];
      __syncthreads();
      #pragma unroll
      for (int i = 0; i < 16; i++) {
        int dr = r4 + i * 4;
        Dq[(size_t)(col0 + dr) * 256 + row0 + c] = (__bf16)tile[c][dr];
      }
    } else {
      // b2u[c] = sum_j mb2[j] * uW1[128+j][c]
      int cc = tid;
      float acc = 0.0f;
      for (int j2 = 0; j2 < 128; j2++)
        acc += mb2[l * 128 + j2] * uW1[(size_t)l * 65536 + (size_t)(128 + j2) * 256 + cc];
      b2u[l * 256 + cc] = acc;
    }
  } else if (bxf < NB_PREP + NB_HIST) {
    int e = (bxf - NB_PREP) * 256 + tid;
    atomicAdd(&counts[dstI[e]], 1);
  } else {
    // embedding: 32 nodes per block, 16 accumulators per thread
    int nb = bxf - (NB_PREP + NB_HIST);
    int n0e = nb * 32;
    float* xsf = (float*)smem;                               // [32][26]
    float (*hid2)[128] = (float(*)[128])(smem + 32 * 26 * 4);
    for (int i = tid; i < 32 * 26; i += 256)
      xsf[i] = x[(size_t)n0e * 26 + i];
    __syncthreads();
    int j = tid & 127, ns = tid >> 7;
    float a1[16];
    {
      float bb = eb1[j];
      #pragma unroll
      for (int i = 0; i < 16; i++) a1[i] = bb;
    }
    for (int k = 0; k < 26; k++) {
      float w = eW1[k * 128 + j];
      #pragma unroll
      for (int i = 0; i < 16; i++) a1[i] += xsf[(ns * 16 + i) * 26 + k] * w;
    }
    #pragma unroll
    for (int i = 0; i < 16; i++) hid2[ns * 16 + i][j] = silu_f(a1[i]);
    __syncthreads();
    float a2[16];
    {
      float bb = eb2[j];
      #pragma unroll
      for (int i = 0; i < 16; i++) a2[i] = bb;
    }
    for (int k = 0; k < 128; k++) {
      float w = eW2[k * 128 + j];
      #pragma unroll
      for (int i = 0; i < 16; i++) a2[i] += hid2[ns * 16 + i][k] * w;
    }
    #pragma unroll
    for (int i = 0; i < 16; i++) {
      int n = n0e + ns * 16 + i;
      h[(size_t)n * 128 + j] = a2[i];
      hb[(size_t)n * 128 + j] = (__bf16)a2[i];
    }
  }
}

// ---------------- zprep (layer 0 only): z1b, z2b; zeros aggH ----------------
__global__ __launch_bounds__(256) void zprep_kernel(
    const __bf16* __restrict__ hb, const float* __restrict__ b1,
    const __bf16* __restrict__ W1at, const __bf16* __restrict__ W1bt,
    __bf16* __restrict__ z1b, __bf16* __restrict__ z2b, float* __restrict__ aggH)
{
  __shared__ __bf16 s_n[64][136];
  int tid = threadIdx.x, n0 = blockIdx.x * 64;
  {
    int n = tid >> 2, t4 = tid & 3;
    const bf16x8* hr = (const bf16x8*)(hb + (size_t)(n0 + n) * 128);
    #pragma unroll
    for (int i = 0; i < 4; i++)
      *(bf16x8*)&s_n[n][t4 * 8 + 32 * i] = hr[t4 + 4 * i];
  }
  {
    float4 zz = make_float4(0.f, 0.f, 0.f, 0.f);
    float4* ap = (float4*)(aggH + (size_t)n0 * 256);
    for (int i = tid; i < 64 * 256 / 4; i += 256) ap[i] = zz;
  }
  __syncthreads();
  const int wv = tid >> 6, ln = tid & 63, lc = ln & 15, qd = ln >> 4;
  for (int cp = 0; cp < 2; cp++) {
    f32x4 aA[4][2], aB[4][2];
    #pragma unroll
    for (int nt = 0; nt < 2; nt++) {
      float bv = b1[cp * 128 + wv * 32 + nt * 16 + lc];
      #pragma unroll
      for (int mt = 0; mt < 4; mt++) {
        aA[mt][nt][0] = 0.f; aA[mt][nt][1] = 0.f;
        aA[mt][nt][2] = 0.f; aA[mt][nt][3] = 0.f;
        aB[mt][nt][0] = bv; aB[mt][nt][1] = bv;
        aB[mt][nt][2] = bv; aB[mt][nt][3] = bv;
      }
    }
    #pragma unroll
    for (int kt = 0; kt < 4; kt++) {
      bf16x8 af[4];
      #pragma unroll
      for (int mt = 0; mt < 4; mt++)
        af[mt] = *(const bf16x8*)&s_n[mt * 16 + lc][kt * 32 + qd * 8];
      bf16x8 bwA[2], bwB[2];
      #pragma unroll
      for (int nt = 0; nt < 2; nt++) {
        int c = cp * 128 + wv * 32 + nt * 16 + lc;
        bwA[nt] = *(const bf16x8*)(W1at + (size_t)c * 128 + kt * 32 + qd * 8);
        bwB[nt] = *(const bf16x8*)(W1bt + (size_t)c * 128 + kt * 32 + qd * 8);
      }
      #pragma unroll
      for (int mt = 0; mt < 4; mt++)
        #pragma unroll
        for (int nt = 0; nt < 2; nt++) {
          aA[mt][nt] = __builtin_amdgcn_mfma_f32_16x16x32_bf16(af[mt], bwA[nt], aA[mt][nt], 0, 0, 0);
          aB[mt][nt] = __builtin_amdgcn_mfma_f32_16x16x32_bf16(af[mt], bwB[nt], aB[mt][nt], 0, 0, 0);
        }
    }
    #pragma unroll
    for (int mt = 0; mt < 4; mt++)
      #pragma unroll
      for (int nt = 0; nt < 2; nt++) {
        int c = cp * 128 + wv * 32 + nt * 16 + lc;
        #pragma unroll
        for (int r = 0; r < 4; r++) {
          int n = n0 + mt * 16 + qd * 4 + r;
          z1b[(size_t)n * 256 + c] = (__bf16)aA[mt][nt][r];
          z2b[(size_t)n * 256 + c] = (__bf16)aB[mt][nt][r];
        }
      }
  }
}

// ---------------- fused message kernel v12: LDS-atomic seg-sum ----------------
// Replaces the s_hT transpose + per-col scan with direct ds_add_f32 into
// s_agg[seg][col] (f32). Per thread, the 4 accumulator rows almost always
// share one segment (byte-equality test on the packed seg word) -> 1 ds_add
// instead of 4. Flush = exactly nseg atomics/col (fewer than the scan's ~5).
// Rare nseg>16 handled by uniform multi-pass recompute. LDS 19.3KB, 8 blk/CU.
__global__ __launch_bounds__(256, 8) void msg_mfma_kernel(
    const __bf16* __restrict__ z1b, const __bf16* __restrict__ z2b,
    const __bf16* __restrict__ efb,
    const int* __restrict__ esrc, const int* __restrict__ edst,
    const __bf16* __restrict__ B2c, float* __restrict__ aggH)
{
  __shared__ float s_agg[16][256];                 // 16384 B
  __shared__ __align__(16) __bf16 s_ef[TE][16];    // 2048 B
  __shared__ int s_src[TE];
  __shared__ int s_dst[TE];
  __shared__ int s_dseg[TE];
  __shared__ unsigned char s_seg[TE];
  __shared__ int s_nseg;

  int tid = threadIdx.x, e0 = blockIdx.x * TE;

  if (tid < TE) {
    int d = edst[e0 + tid];
    s_dst[tid] = d;
    int dp = (tid == 0) ? (d ^ 1) : edst[e0 + tid - 1];
    unsigned long long mb = __ballot(d != dp);
    unsigned long long below = mb & (~0ull >> (63 - tid));
    int seg = (int)__popcll(below) - 1;   // bit0 always set -> seg(0)=0
    s_seg[tid] = (unsigned char)seg;
    if (d != dp) s_dseg[seg] = d;
    if (tid == 0) s_nseg = (int)__popcll(mb);
  } else if (tid < 2 * TE) {
    s_src[tid - TE] = esrc[e0 + tid - TE];
  }
  {
    int e = tid >> 2, t4 = tid & 3;
    if (t4 < 2)
      *(bf16x8*)&s_ef[e][t4 * 8] =
          *(const bf16x8*)(efb + (size_t)(e0 + e) * 16 + t4 * 8);
  }
  #pragma unroll
  for (int r = 0; r < 16; r++) s_agg[r][tid] = 0.0f;
  __syncthreads();

  const int wv = tid >> 6, ln = tid & 63, lc = ln & 15, qd = ln >> 4;
  const int nseg = __builtin_amdgcn_readfirstlane(s_nseg);

  // identity B fragment: C[e][c] = A[e][c] + A[e][c+16] (z1[src]+z2[dst])
  bf16x8 bI;
  #pragma unroll
  for (int j = 0; j < 8; j++)
    bI[j] = (__bf16)((lc == (qd & 1) * 8 + j) ? 1.0f : 0.0f);

  // z row pointers: qd<2 supplies z1[src] k-halves, qd>=2 z2[dst]
  const __bf16* pz[4];
  #pragma unroll
  for (int mt = 0; mt < 4; mt++) {
    int m = mt * 16 + lc;
    int row = (qd < 2) ? s_src[m] : s_dst[m];
    pz[mt] = ((qd < 2) ? z1b : z2b) + (size_t)row * 256 + (qd & 1) * 8;
  }

  // ef A-fragments (rows = edges)
  bf16x8 aef[4];
  #pragma unroll
  for (int mt = 0; mt < 4; mt++)
    aef[mt] = *(const bf16x8*)&s_ef[mt * 16 + lc][(qd & 1) * 8];

  // packed segment words for this lane's 4 rows per window mt
  unsigned int sw[4];
  int sg0[4];
  bool eqm[4];
  #pragma unroll
  for (int mt = 0; mt < 4; mt++) {
    sw[mt] = *(const unsigned int*)&s_seg[mt * 16 + qd * 4];
    sg0[mt] = (int)(sw[mt] & 255u);
    eqm[mt] = (sw[mt] == (sw[mt] & 255u) * 0x01010101u);
  }

  if (nseg <= 16) {
    // ---- fast path (overwhelmingly common) ----
    #pragma unroll
    for (int hf = 0; hf < 2; hf++) {
      #pragma unroll
      for (int nt = 0; nt < 2; nt++) {
        const int cb = hf * 128 + wv * 32 + nt * 16;
        bf16x8 bw = *(const bf16x8*)(B2c + (size_t)(cb + lc) * 32 + qd * 8);
        const int col = cb + lc;
        #pragma unroll
        for (int mt = 0; mt < 4; mt++) {
          bf16x8 az = *(const bf16x8*)(pz[mt] + cb);
          f32x4 z; z[0] = 0.f; z[1] = 0.f; z[2] = 0.f; z[3] = 0.f;
          f32x4 acc = __builtin_amdgcn_mfma_f32_16x16x32_bf16(az, bI, z, 0, 0, 0);
          acc = __builtin_amdgcn_mfma_f32_16x16x32_bf16(aef[mt], bw, acc, 0, 0, 0);
          float p0 = silu_f(acc[0]), p1 = silu_f(acc[1]);
          float p2 = silu_f(acc[2]), p3 = silu_f(acc[3]);
          if (eqm[mt]) {
            atomicAdd(&s_agg[sg0[mt]][col], (p0 + p1) + (p2 + p3));
          } else {
            atomicAdd(&s_agg[(sw[mt] >> 0) & 255][col], p0);
            atomicAdd(&s_agg[(sw[mt] >> 8) & 255][col], p1);
            atomicAdd(&s_agg[(sw[mt] >> 16) & 255][col], p2);
            atomicAdd(&s_agg[(sw[mt] >> 24) & 255][col], p3);
          }
        }
      }
    }
    __syncthreads();
    for (int r = 0; r < nseg; r++)
      atomicAdd(&aggH[(size_t)s_dseg[r] * 256 + tid], s_agg[r][tid]);
  } else {
    // ---- rare multi-pass path (nseg > 16) ----
    for (int ps = 0; ps < nseg; ps += 16) {
      if (ps > 0) {
        __syncthreads();
        #pragma unroll
        for (int r = 0; r < 16; r++) s_agg[r][tid] = 0.0f;
        __syncthreads();
      }
      #pragma unroll
      for (int hf = 0; hf < 2; hf++) {
        #pragma unroll
        for (int nt = 0; nt < 2; nt++) {
          const int cb = hf * 128 + wv * 32 + nt * 16;
          bf16x8 bw = *(const bf16x8*)(B2c + (size_t)(cb + lc) * 32 + qd * 8);
          const int col = cb + lc;
          #pragma unroll
          for (int mt = 0; mt < 4; mt++) {
            bf16x8 az = *(const bf16x8*)(pz[mt] + cb);
            f32x4 z; z[0] = 0.f; z[1] = 0.f; z[2] = 0.f; z[3] = 0.f;
            f32x4 acc = __builtin_amdgcn_mfma_f32_16x16x32_bf16(az, bI, z, 0, 0, 0);
            acc = __builtin_amdgcn_mfma_f32_16x16x32_bf16(aef[mt], bw, acc, 0, 0, 0);
            #pragma unroll
            for (int r = 0; r < 4; r++) {
              int s = (int)((sw[mt] >> (8 * r)) & 255u) - ps;
              if ((unsigned)s < 16u)
                atomicAdd(&s_agg[s][col], silu_f(acc[r]));
            }
          }
        }
      }
      __syncthreads();
      int rows = nseg - ps; if (rows > 16) rows = 16;
      for (int r = 0; r < rows; r++)
        atomicAdd(&aggH[(size_t)s_dseg[ps + r] * 256 + tid], s_agg[r][tid]);
    }
  }
}

// ---------------- fused node update MLP v4 (round-4 verbatim, proven) ----------------
__global__ __launch_bounds__(512, 2) void upd_mfma_kernel(
    float* __restrict__ h, __bf16* __restrict__ hb,
    float* __restrict__ aggH, const float* __restrict__ degf,
    const __bf16* __restrict__ uW1ft, const float* __restrict__ b1,
    const float* __restrict__ b2u,
    const __bf16* __restrict__ uW2t, const float* __restrict__ b2,
    int do_z, const float* __restrict__ nb1,
    const __bf16* __restrict__ nW1at, const __bf16* __restrict__ nW1bt,
    __bf16* __restrict__ z1b, __bf16* __restrict__ z2b)
{
  __shared__ __bf16 s_u[64][392];    // [h(128) | agg(256)] + 8 pad
  __shared__ __bf16 s_uh[64][264];   // 256 hidden cols + 8 pad
  int tid = threadIdx.x, n0 = blockIdx.x * 64;
  {
    int n = tid >> 3, t8 = tid & 7;  // 8 threads per node
    const bf16x8* hr = (const bf16x8*)(hb + (size_t)(n0 + n) * 128);
    #pragma unroll
    for (int i = 0; i < 2; i++)
      *(bf16x8*)&s_u[n][t8 * 8 + 64 * i] = hr[t8 + 8 * i];
    const float* sr = aggH + (size_t)(n0 + n) * 256;
    #pragma unroll
    for (int i = 0; i < 4; i++) {
      int col = t8 * 8 + i * 64;
      float4 a = *(const float4*)(sr + col);
      float4 b = *(const float4*)(sr + col + 4);
      bf16x8 o;
      o[0] = (__bf16)a.x; o[1] = (__bf16)a.y; o[2] = (__bf16)a.z; o[3] = (__bf16)a.w;
      o[4] = (__bf16)b.x; o[5] = (__bf16)b.y; o[6] = (__bf16)b.z; o[7] = (__bf16)b.w;
      *(bf16x8*)&s_u[n][128 + col] = o;
    }
  }
  __syncthreads();
  const int wv = tid >> 6, ln = tid & 63, lc = ln & 15, qd = ln >> 4;  // wv 0..7

  float dg[4][4];
  #pragma unroll
  for (int mt = 0; mt < 4; mt++)
    #pragma unroll
    for (int r = 0; r < 4; r++)
      dg[mt][r] = degf[n0 + mt * 16 + qd * 4 + r];

  // ---- GEMM1: K=384, wave owns cols wv*32 + nt*16 + lc ----
  {
    f32x4 acc1[4][2];
    #pragma unroll
    for (int nt = 0; nt < 2; nt++) {
      int c = wv * 32 + nt * 16 + lc;
      float bv = b1[c];
      float b2uv = b2u[c];
      #pragma unroll
      for (int mt = 0; mt < 4; mt++)
        #pragma unroll
        for (int r = 0; r < 4; r++)
          acc1[mt][nt][r] = bv + dg[mt][r] * b2uv;
    }
    #pragma unroll
    for (int kt = 0; kt < 12; kt++) {
      bf16x8 af[4];
      #pragma unroll
      for (int mt = 0; mt < 4; mt++)
        af[mt] = *(const bf16x8*)&s_u[mt * 16 + lc][kt * 32 + qd * 8];
      bf16x8 bw[2];
      #pragma unroll
      for (int nt = 0; nt < 2; nt++)
        bw[nt] = *(const bf16x8*)(uW1ft +
                 (size_t)(wv * 32 + nt * 16 + lc) * 384 + kt * 32 + qd * 8);
      #pragma unroll
      for (int mt = 0; mt < 4; mt++)
        #pragma unroll
        for (int nt = 0; nt < 2; nt++)
          acc1[mt][nt] = __builtin_amdgcn_mfma_f32_16x16x32_bf16(af[mt], bw[nt], acc1[mt][nt], 0, 0, 0);
    }
    #pragma unroll
    for (int mt = 0; mt < 4; mt++)
      #pragma unroll
      for (int nt = 0; nt < 2; nt++) {
        int cc = wv * 32 + nt * 16 + lc;
        #pragma unroll
        for (int r = 0; r < 4; r++)
          s_uh[mt * 16 + qd * 4 + r][cc] = (__bf16)silu_f(acc1[mt][nt][r]);
      }
  }
  __syncthreads();

  // ---- GEMM2: K=256, wave owns output cols ow = wv*16 + lc ----
  const int ow = wv * 16 + lc;
  f32x4 acc2[4];
  {
    float bv = b2[ow];
    #pragma unroll
    for (int mt = 0; mt < 4; mt++) {
      acc2[mt][0] = bv; acc2[mt][1] = bv; acc2[mt][2] = bv; acc2[mt][3] = bv;
    }
  }
  #pragma unroll
  for (int kt = 0; kt < 8; kt++) {
    bf16x8 a2[4];
    #pragma unroll
    for (int mt = 0; mt < 4; mt++)
      a2[mt] = *(const bf16x8*)&s_uh[mt * 16 + lc][kt * 32 + qd * 8];
    bf16x8 b2w = *(const bf16x8*)(uW2t + (size_t)ow * 256 + kt * 32 + qd * 8);
    #pragma unroll
    for (int mt = 0; mt < 4; mt++)
      acc2[mt] = __builtin_amdgcn_mfma_f32_16x16x32_bf16(a2[mt], b2w, acc2[mt], 0, 0, 0);
  }

  // residual epilogue
  #pragma unroll
  for (int mt = 0; mt < 4; mt++)
    #pragma unroll
    for (int r = 0; r < 4; r++) {
      int n = n0 + mt * 16 + qd * 4 + r;
      float v = h[(size_t)n * 128 + ow] + acc2[mt][r];
      h[(size_t)n * 128 + ow] = v;
      hb[(size_t)n * 128 + ow] = (__bf16)v;
    }

  // ---- fused zprep for next layer ----
  if (do_z) {
    __syncthreads();
    {
      float4 zz = make_float4(0.f, 0.f, 0.f, 0.f);
      float4* ap = (float4*)(aggH + (size_t)n0 * 256);
      for (int i = tid; i < 64 * 256 / 4; i += 512) ap[i] = zz;
      int n = tid >> 3, t8 = tid & 7;
      const bf16x8* hr = (const bf16x8*)(hb + (size_t)(n0 + n) * 128);
      #pragma unroll
      for (int i = 0; i < 2; i++)
        *(bf16x8*)&s_u[n][t8 * 8 + 64 * i] = hr[t8 + 8 * i];
    }
    __syncthreads();
    f32x4 aA[4][2], aB[4][2];
    #pragma unroll
    for (int nt = 0; nt < 2; nt++) {
      float bv = nb1[wv * 32 + nt * 16 + lc];
      #pragma unroll
      for (int mt = 0; mt < 4; mt++) {
        aA[mt][nt][0] = 0.f; aA[mt][nt][1] = 0.f;
        aA[mt][nt][2] = 0.f; aA[mt][nt][3] = 0.f;
        aB[mt][nt][0] = bv; aB[mt][nt][1] = bv;
        aB[mt][nt][2] = bv; aB[mt][nt][3] = bv;
      }
    }
    #pragma unroll
    for (int kt = 0; kt < 4; kt++) {
      bf16x8 af[4];
      #pragma unroll
      for (int mt = 0; mt < 4; mt++)
        af[mt] = *(const bf16x8*)&s_u[mt * 16 + lc][kt * 32 + qd * 8];
      bf16x8 bwA[2], bwB[2];
      #pragma unroll
      for (int nt = 0; nt < 2; nt++) {
        int c = wv * 32 + nt * 16 + lc;
        bwA[nt] = *(const bf16x8*)(nW1at + (size_t)c * 128 + kt * 32 + qd * 8);
        bwB[nt] = *(const bf16x8*)(nW1bt + (size_t)c * 128 + kt * 32 + qd * 8);
      }
      #pragma unroll
      for (int mt = 0; mt < 4; mt++)
        #pragma unroll
        for (int nt = 0; nt < 2; nt++) {
          aA[mt][nt] = __builtin_amdgcn_mfma_f32_16x16x32_bf16(af[mt], bwA[nt], aA[mt][nt], 0, 0, 0);
          aB[mt][nt] = __builtin_amdgcn_mfma_f32_16x16x32_bf16(af[mt], bwB[nt], aB[mt][nt], 0, 0, 0);
        }
    }
    #pragma unroll
    for (int mt = 0; mt < 4; mt++)
      #pragma unroll
      for (int nt = 0; nt < 2; nt++) {
        int c = wv * 32 + nt * 16 + lc;
        #pragma unroll
        for (int r = 0; r < 4; r++) {
          int n = n0 + mt * 16 + qd * 4 + r;
          z1b[(size_t)n * 256 + c] = (__bf16)aA[mt][nt][r];
          z2b[(size_t)n * 256 + c] = (__bf16)aB[mt][nt][r];
        }
      }
  }
}

// ---------------- readout ----------------
__global__ __launch_bounds__(128) void readout_sum_kernel(
    const float* __restrict__ h, const int* __restrict__ batch,
    float* __restrict__ gsum, float* __restrict__ gcnt)
{
  int j = threadIdx.x;
  int n0 = blockIdx.x * 128;
  float acc = 0.f, cacc = 0.f;
  int cur = batch[n0];
  for (int i = 0; i < 128; i++) {
    int b = batch[n0 + i];
    if (b != cur) {
      atomicAdd(&gsum[cur * 128 + j], acc);
      if (j == 0) atomicAdd(&gcnt[cur], cacc);
      acc = 0.f; cacc = 0.f; cur = b;
    }
    acc += h[(size_t)(n0 + i) * 128 + j];
    cacc += 1.f;
  }
  atomicAdd(&gsum[cur * 128 + j], acc);
  if (j == 0) atomicAdd(&gcnt[cur], cacc);
}

__global__ __launch_bounds__(256) void readout_mlp_kernel(
    const float* __restrict__ gsum, const float* __restrict__ gcnt,
    const float* __restrict__ W1, const float* __restrict__ b1,
    const float* __restrict__ W2, const float* __restrict__ b2,
    float* __restrict__ out)
{
  __shared__ float g[8][128];
  __shared__ float hid[8][256];
  int tid = threadIdx.x;
  for (int i = tid; i < 8 * 128; i += 256) {
    int b = i >> 7, c = i & 127;
    g[b][c] = gsum[i] / fmaxf(gcnt[b], 1.0f);
  }
  __syncthreads();
  {
    float bb = b1[tid];
    float a[8];
    #pragma unroll
    for (int b = 0; b < 8; b++) a[b] = bb;
    for (int k = 0; k < 128; k++) {
      float w = W1[k * 256 + tid];
      #pragma unroll
      for (int b = 0; b < 8; b++) a[b] += g[b][k] * w;
    }
    #pragma unroll
    for (int b = 0; b < 8; b++) hid[b][tid] = silu_f(a[b]);
  }
  __syncthreads();
  int j = tid & 63, bg = tid >> 6;
  float a0 = b2[j], a1 = b2[j];
  for (int k = 0; k < 256; k++) {
    float w = W2[k * 64 + j];
    a0 += hid[bg * 2 + 0][k] * w;
    a1 += hid[bg * 2 + 1][k] * w;
  }
  out[(bg * 2 + 0) * 64 + j] = a0;
  out[(bg * 2 + 1) * 64 + j] = a1;
}

extern "C" void kernel_launch(void* const* d_in, const int* in_sizes, int n_in,
                              void* d_out, int out_size, void* d_ws, size_t ws_size,
                              hipStream_t stream) {
  const float* pos   = (const float*)d_in[0];
  const float* xfeat = (const float*)d_in[1];
  const int*   eidx  = (const int*)d_in[2];
  const int*   batch = (const int*)d_in[3];
  const float* eW1 = (const float*)d_in[4];
  const float* eb1 = (const float*)d_in[5];
  const float* eW2 = (const float*)d_in[6];
  const float* eb2 = (const float*)d_in[7];
  const float* mW1 = (const float*)d_in[8];
  const float* mb1 = (const float*)d_in[9];
  const float* mW2 = (const float*)d_in[10];
  const float* mb2 = (const float*)d_in[11];
  const float* uW1 = (const float*)d_in[12];
  const float* ub1 = (const float*)d_in[13];
  const float* uW2 = (const float*)d_in[14];
  const float* ub2 = (const float*)d_in[15];
  const float* rW1 = (const float*)d_in[16];
  const float* rb1 = (const float*)d_in[17];
  const float* rW2 = (const float*)d_in[18];
  const float* rb2 = (const float*)d_in[19];

  const int* srcI = eidx;
  const int* dstI = eidx + NEDGES;

  char* base = (char*)d_ws;
  float* h    = (float*)base;  base += (size_t)NATOMS * 128 * 4;
  float* aggH = (float*)base;  base += (size_t)NATOMS * 256 * 4;
  __bf16* z1b = (__bf16*)base; base += (size_t)NATOMS * 256 * 2;
  __bf16* z2b = (__bf16*)base; base += (size_t)NATOMS * 256 * 2;
  __bf16* hb  = (__bf16*)base; base += (size_t)NATOMS * 128 * 2;
  __bf16* efb = (__bf16*)base; base += (size_t)NEDGES * 16 * 2;
  __bf16* W1at = (__bf16*)base; base += (size_t)NLAYERS * 256 * 128 * 2;
  __bf16* W1bt = (__bf16*)base; base += (size_t)NLAYERS * 256 * 128 * 2;
  __bf16* B2c  = (__bf16*)base; base += (size_t)NLAYERS * 256 * 32 * 2;
  __bf16* uW1ft = (__bf16*)base; base += (size_t)NLAYERS * 256 * 384 * 2;
  __bf16* uW2t = (__bf16*)base; base += (size_t)NLAYERS * 128 * 256 * 2;
  float* b2u  = (float*)base;  base += (size_t)NLAYERS * 256 * 4;
  float* degf = (float*)base;  base += (size_t)NATOMS * 4;
  float* gsum = (float*)base;  base += 8 * 128 * 4;
  float* gcnt = (float*)base;  base += 8 * 4;
  int* counts = (int*)base;    base += (size_t)NATOMS * 4;
  int* cursor = (int*)base;    base += (size_t)NATOMS * 4;
  int* esrc   = (int*)base;    base += (size_t)NEDGES * 4;
  int* edst   = (int*)base;    base += (size_t)NEDGES * 4;

  // counts must be zeroed before front_kernel's hist section
  hipMemsetAsync(counts, 0, NATOMS * sizeof(int), stream);

  // merged front: weight prep + dst histogram + embedding
  front_kernel<<<NB_PREP + NB_HIST + NB_EMB, 256, 0, stream>>>(
      mW1, mW2, uW1, uW2, mb2, W1at, W1bt, B2c, uW1ft, uW2t, b2u,
      dstI, counts, xfeat, eW1, eb1, eW2, eb2, h, hb);

  scan_kernel<<<1, 1024, 0, stream>>>(counts, cursor, degf);
  scatter_rbf_kernel<<<NEDGES / 256, 256, 0, stream>>>(
      srcI, dstI, cursor, pos, esrc, edst, efb);

  // zprep for layer 0 (also zeros aggH)
  zprep_kernel<<<NATOMS / 64, 256, 0, stream>>>(
      hb, mb1, W1at, W1bt, z1b, z2b, aggH);

  for (int l = 0; l < NLAYERS; l++) {
    int ln = (l < NLAYERS - 1) ? (l + 1) : l;
    msg_mfma_kernel<<<NEDGES / TE, 256, 0, stream>>>(
        z1b, z2b, efb, esrc, edst,
        B2c + (size_t)l * 256 * 32, aggH);
    upd_mfma_kernel<<<NATOMS / 64, 512, 0, stream>>>(
        h, hb, aggH, degf,
        uW1ft + (size_t)l * 256 * 384, ub1 + (size_t)l * 256,
        b2u + (size_t)l * 256,
        uW2t + (size_t)l * 128 * 256, ub2 + (size_t)l * 128,
        (l < NLAYERS - 1) ? 1 : 0,
        mb1 + (size_t)ln * 256,
        W1at + (size_t)ln * 256 * 128, W1bt + (size_t)ln * 256 * 128,
        z1b, z2b);
  }

  hipMemsetAsync(gsum, 0, (8 * 128 + 8) * sizeof(float), stream);
  readout_sum_kernel<<<NATOMS / 128, 128, 0, stream>>>(h, batch, gsum, gcnt);
  readout_mlp_kernel<<<1, 256, 0, stream>>>(gsum, gcnt, rW1, rb1, rW2, rb2,
                                            (float*)d_out);
}

// Round 9
// 582.865 us; speedup vs baseline: 2.2022x; 2.2022x over previous
//
#include <hip/hip_runtime.h>
#include <math.h>

#define NATOMS 16384
#define NEDGES 524288
#define NLAYERS 4
#define TE 64      // edges per block in msg kernel

typedef __bf16 bf16x8 __attribute__((ext_vector_type(8)));
typedef __bf16 bf16x4 __attribute__((ext_vector_type(4)));
typedef __bf16 bf16x2 __attribute__((ext_vector_type(2)));
typedef float f32x4 __attribute__((ext_vector_type(4)));

// fast silu: x * rcp(1+exp(-x))
__device__ __forceinline__ float silu_f(float x) {
  return x * __builtin_amdgcn_rcpf(1.0f + __expf(-x));
}

// ---------------- CSR preprocessing ----------------
__global__ __launch_bounds__(1024) void scan_kernel(
    const int* __restrict__ counts, int* __restrict__ cursor,
    float* __restrict__ degf)
{
  __shared__ int s_tot[1024];
  int tid = threadIdx.x;
  int v[16];
  {
    const int4* cp = (const int4*)(counts + tid * 16);
    int4 a = cp[0], b = cp[1], c = cp[2], d = cp[3];
    v[0]=a.x; v[1]=a.y; v[2]=a.z; v[3]=a.w;
    v[4]=b.x; v[5]=b.y; v[6]=b.z; v[7]=b.w;
    v[8]=c.x; v[9]=c.y; v[10]=c.z; v[11]=c.w;
    v[12]=d.x; v[13]=d.y; v[14]=d.z; v[15]=d.w;
  }
  int tot = 0;
  #pragma unroll
  for (int i = 0; i < 16; i++) tot += v[i];
  s_tot[tid] = tot;
  __syncthreads();
  for (int off = 1; off < 1024; off <<= 1) {
    int t = (tid >= off) ? s_tot[tid - off] : 0;
    __syncthreads();
    s_tot[tid] += t;
    __syncthreads();
  }
  int run = s_tot[tid] - tot;   // exclusive prefix
  #pragma unroll
  for (int i = 0; i < 16; i++) {
    cursor[tid * 16 + i] = run;
    degf[tid * 16 + i] = (float)v[i];
    run += v[i];
  }
}

// scatter + RBF fused: each edge computes its sorted slot p, writes esrc/edst
// AND its RBF features directly to efb[p].
__global__ __launch_bounds__(256) void scatter_rbf_kernel(
    const int* __restrict__ src, const int* __restrict__ dst,
    int* __restrict__ cursor, const float* __restrict__ pos,
    int* __restrict__ esrc, int* __restrict__ edst,
    __bf16* __restrict__ efb)
{
  int e = blockIdx.x * 256 + threadIdx.x;
  int s = src[e], d = dst[e];
  int p = atomicAdd(&cursor[d], 1);
  esrc[p] = s;
  edst[p] = d;
  float dx = pos[d * 3 + 0] - pos[s * 3 + 0];
  float dy = pos[d * 3 + 1] - pos[s * 3 + 1];
  float dz = pos[d * 3 + 2] - pos[s * 3 + 2];
  float dist = sqrtf(dx * dx + dy * dy + dz * dz + 1e-12f);
  float env = (dist < 10.0f)
                  ? 0.5f * (cosf(3.14159265358979f * dist * 0.1f) + 1.0f)
                  : 0.0f;
  bf16x8 o0, o1;
  #pragma unroll
  for (int i = 0; i < 16; i++) {
    float c = (10.0f / 15.0f) * (float)i;
    float t = dist - c;
    float v = env * __expf(-t * t * 1.28f);
    if (i < 8) o0[i] = (__bf16)v; else o1[i - 8] = (__bf16)v;
  }
  *(bf16x8*)(efb + (size_t)p * 16 + 0) = o0;
  *(bf16x8*)(efb + (size_t)p * 16 + 8) = o1;
}

// ---------------- merged front kernel v2 ----------------
// prep: LDS-tiled 64x64 transposes (coalesced both sides),
// 16-row-slab fusion GEMM (16-way ILP), 32-node embed blocks.
#define NB_PL   50
#define NB_PREP (NB_PL * NLAYERS)
#define NB_HIST (NEDGES / 256)
#define NB_EMB  (NATOMS / 32)

__global__ __launch_bounds__(256) void front_kernel(
    const float* __restrict__ mW1, const float* __restrict__ mW2,
    const float* __restrict__ uW1, const float* __restrict__ uW2,
    const float* __restrict__ mb2,
    __bf16* __restrict__ W1at, __bf16* __restrict__ W1bt,
    __bf16* __restrict__ B2c, __bf16* __restrict__ uW1ft,
    __bf16* __restrict__ uW2t, float* __restrict__ b2u,
    const int* __restrict__ dstI, int* __restrict__ counts,
    const float* __restrict__ x, const float* __restrict__ eW1,
    const float* __restrict__ eb1, const float* __restrict__ eW2,
    const float* __restrict__ eb2, float* __restrict__ h,
    __bf16* __restrict__ hb)
{
  __shared__ __align__(16) char smem[19712];
  int bxf = blockIdx.x, tid = threadIdx.x;

  if (bxf < NB_PREP) {
    int l = bxf / NB_PL;
    int bx = bxf - l * NB_PL;
    if (bx < 16) {
      // W1at / W1bt: transpose 64x64 tiles of mW1 rows [0,256)
      float (*tile)[65] = (float(*)[65])smem;
      int tt = bx & 7;
      int row0 = ((tt >> 2) * 64) + ((bx < 8) ? 0 : 128);   // source k-row
      int col0 = (tt & 3) * 64;                             // source col (c)
      const float* Sp = mW1 + (size_t)l * (272 * 256) + (size_t)row0 * 256 + col0;
      __bf16* Dq = ((bx < 8) ? W1at : W1bt) + (size_t)l * (256 * 128);
      int dro = (bx < 8) ? row0 : row0 - 128;
      int c = tid & 63, r4 = tid >> 6;
      #pragma unroll
      for (int i = 0; i < 16; i++)
        tile[r4 + i * 4][c] = Sp[(size_t)(r4 + i * 4) * 256 + c];
      __syncthreads();
      #pragma unroll
      for (int i = 0; i < 16; i++) {
        int dr = r4 + i * 4;
        Dq[(size_t)(col0 + dr) * 128 + dro + c] = (__bf16)tile[c][dr];
      }
    } else if (bx == 16) {
      // B2c: rows 256..271 of mW1 -> [c][k] with zero pad to k=32
      float (*t3)[257] = (float(*)[257])smem;
      const float* Sp = mW1 + (size_t)l * (272 * 256) + 256 * 256;
      #pragma unroll
      for (int i = 0; i < 16; i++) t3[i][tid] = Sp[i * 256 + tid];
      __syncthreads();
      __bf16* Dp = B2c + (size_t)l * (256 * 32) + (size_t)tid * 32;
      #pragma unroll
      for (int g = 0; g < 4; g++) {
        bf16x8 o;
        #pragma unroll
        for (int j2 = 0; j2 < 8; j2++) {
          int k = g * 8 + j2;
          o[j2] = (__bf16)((k < 16) ? t3[k][tid] : 0.0f);
        }
        *(bf16x8*)(Dp + g * 8) = o;
      }
    } else if (bx < 25) {
      // uW1ft copy part (k<128): transpose 64x64 tiles of uW1
      float (*tile)[65] = (float(*)[65])smem;
      int tt = bx - 17;
      int row0 = (tt >> 2) * 64;         // k
      int col0 = (tt & 3) * 64;          // n
      const float* Sp = uW1 + (size_t)l * 65536 + (size_t)row0 * 256 + col0;
      __bf16* Dq = uW1ft + (size_t)l * (256 * 384);
      int c = tid & 63, r4 = tid >> 6;
      #pragma unroll
      for (int i = 0; i < 16; i++)
        tile[r4 + i * 4][c] = Sp[(size_t)(r4 + i * 4) * 256 + c];
      __syncthreads();
      #pragma unroll
      for (int i = 0; i < 16; i++) {
        int dr = r4 + i * 4;
        Dq[(size_t)(col0 + dr) * 384 + row0 + c] = (__bf16)tile[c][dr];
      }
    } else if (bx < 41) {
      // fusion slab: F[r0+r][n] = sum_j mW2[r0+r][j] * uW1[128+j][n]
      float (*sA)[128] = (float(*)[128])smem;
      int r0 = (bx - 25) * 16;
      const float* Ap = mW2 + (size_t)(l * 256 + r0) * 128;
      #pragma unroll
      for (int i = 0; i < 8; i++) {
        int idx = i * 256 + tid;
        ((float*)smem)[idx] = Ap[idx];
      }
      __syncthreads();
      const float* Bp = uW1 + (size_t)l * 65536 + 128 * 256 + tid;
      float acc[16];
      #pragma unroll
      for (int r = 0; r < 16; r++) acc[r] = 0.0f;
      for (int k = 0; k < 128; k++) {
        float b = Bp[(size_t)k * 256];
        #pragma unroll
        for (int r = 0; r < 16; r++) acc[r] += sA[r][k] * b;
      }
      __bf16* Dp = uW1ft + (size_t)l * (256 * 384) + (size_t)tid * 384 + 128 + r0;
      bf16x8 o0, o1;
      #pragma unroll
      for (int r = 0; r < 8; r++) { o0[r] = (__bf16)acc[r]; o1[r] = (__bf16)acc[8 + r]; }
      *(bf16x8*)Dp = o0;
      *(bf16x8*)(Dp + 8) = o1;
    } else if (bx < 49) {
      // uW2t: transpose 64x64 tiles of uW2 (256x128)
      float (*tile)[65] = (float(*)[65])smem;
      int tt = bx - 41;
      int row0 = (tt >> 1) * 64;     // k in [0,256)
      int col0 = (tt & 1) * 64;      // n in [0,128)
      const float* Sp = uW2 + (size_t)l * (256 * 128) + (size_t)row0 * 128 + col0;
      __bf16* Dq = uW2t + (size_t)l * (128 * 256);
      int c = tid & 63, r4 = tid >> 6;
      #pragma unroll
      for (int i = 0; i < 16; i++)
        tile[r4 + i * 4][c] = Sp[(size_t)(r4 + i * 4) * 128 + c];
      __syncthreads();
      #pragma unroll
      for (int i = 0; i < 16; i++) {
        int dr = r4 + i * 4;
        Dq[(size_t)(col0 + dr) * 256 + row0 + c] = (__bf16)tile[c][dr];
      }
    } else {
      // b2u[c] = sum_j mb2[j] * uW1[128+j][c]
      int cc = tid;
      float acc = 0.0f;
      for (int j2 = 0; j2 < 128; j2++)
        acc += mb2[l * 128 + j2] * uW1[(size_t)l * 65536 + (size_t)(128 + j2) * 256 + cc];
      b2u[l * 256 + cc] = acc;
    }
  } else if (bxf < NB_PREP + NB_HIST) {
    int e = (bxf - NB_PREP) * 256 + tid;
    atomicAdd(&counts[dstI[e]], 1);
  } else {
    // embedding: 32 nodes per block, 16 accumulators per thread
    int nb = bxf - (NB_PREP + NB_HIST);
    int n0e = nb * 32;
    float* xsf = (float*)smem;                               // [32][26]
    float (*hid2)[128] = (float(*)[128])(smem + 32 * 26 * 4);
    for (int i = tid; i < 32 * 26; i += 256)
      xsf[i] = x[(size_t)n0e * 26 + i];
    __syncthreads();
    int j = tid & 127, ns = tid >> 7;
    float a1[16];
    {
      float bb = eb1[j];
      #pragma unroll
      for (int i = 0; i < 16; i++) a1[i] = bb;
    }
    for (int k = 0; k < 26; k++) {
      float w = eW1[k * 128 + j];
      #pragma unroll
      for (int i = 0; i < 16; i++) a1[i] += xsf[(ns * 16 + i) * 26 + k] * w;
    }
    #pragma unroll
    for (int i = 0; i < 16; i++) hid2[ns * 16 + i][j] = silu_f(a1[i]);
    __syncthreads();
    float a2[16];
    {
      float bb = eb2[j];
      #pragma unroll
      for (int i = 0; i < 16; i++) a2[i] = bb;
    }
    for (int k = 0; k < 128; k++) {
      float w = eW2[k * 128 + j];
      #pragma unroll
      for (int i = 0; i < 16; i++) a2[i] += hid2[ns * 16 + i][k] * w;
    }
    #pragma unroll
    for (int i = 0; i < 16; i++) {
      int n = n0e + ns * 16 + i;
      h[(size_t)n * 128 + j] = a2[i];
      hb[(size_t)n * 128 + j] = (__bf16)a2[i];
    }
  }
}

// ---------------- zprep (layer 0 only): z1b, z2b; zeros aggH ----------------
__global__ __launch_bounds__(256) void zprep_kernel(
    const __bf16* __restrict__ hb, const float* __restrict__ b1,
    const __bf16* __restrict__ W1at, const __bf16* __restrict__ W1bt,
    __bf16* __restrict__ z1b, __bf16* __restrict__ z2b, float* __restrict__ aggH)
{
  __shared__ __bf16 s_n[64][136];
  int tid = threadIdx.x, n0 = blockIdx.x * 64;
  {
    int n = tid >> 2, t4 = tid & 3;
    const bf16x8* hr = (const bf16x8*)(hb + (size_t)(n0 + n) * 128);
    #pragma unroll
    for (int i = 0; i < 4; i++)
      *(bf16x8*)&s_n[n][t4 * 8 + 32 * i] = hr[t4 + 4 * i];
  }
  {
    float4 zz = make_float4(0.f, 0.f, 0.f, 0.f);
    float4* ap = (float4*)(aggH + (size_t)n0 * 256);
    for (int i = tid; i < 64 * 256 / 4; i += 256) ap[i] = zz;
  }
  __syncthreads();
  const int wv = tid >> 6, ln = tid & 63, lc = ln & 15, qd = ln >> 4;
  for (int cp = 0; cp < 2; cp++) {
    f32x4 aA[4][2], aB[4][2];
    #pragma unroll
    for (int nt = 0; nt < 2; nt++) {
      float bv = b1[cp * 128 + wv * 32 + nt * 16 + lc];
      #pragma unroll
      for (int mt = 0; mt < 4; mt++) {
        aA[mt][nt][0] = 0.f; aA[mt][nt][1] = 0.f;
        aA[mt][nt][2] = 0.f; aA[mt][nt][3] = 0.f;
        aB[mt][nt][0] = bv; aB[mt][nt][1] = bv;
        aB[mt][nt][2] = bv; aB[mt][nt][3] = bv;
      }
    }
    #pragma unroll
    for (int kt = 0; kt < 4; kt++) {
      bf16x8 af[4];
      #pragma unroll
      for (int mt = 0; mt < 4; mt++)
        af[mt] = *(const bf16x8*)&s_n[mt * 16 + lc][kt * 32 + qd * 8];
      bf16x8 bwA[2], bwB[2];
      #pragma unroll
      for (int nt = 0; nt < 2; nt++) {
        int c = cp * 128 + wv * 32 + nt * 16 + lc;
        bwA[nt] = *(const bf16x8*)(W1at + (size_t)c * 128 + kt * 32 + qd * 8);
        bwB[nt] = *(const bf16x8*)(W1bt + (size_t)c * 128 + kt * 32 + qd * 8);
      }
      #pragma unroll
      for (int mt = 0; mt < 4; mt++)
        #pragma unroll
        for (int nt = 0; nt < 2; nt++) {
          aA[mt][nt] = __builtin_amdgcn_mfma_f32_16x16x32_bf16(af[mt], bwA[nt], aA[mt][nt], 0, 0, 0);
          aB[mt][nt] = __builtin_amdgcn_mfma_f32_16x16x32_bf16(af[mt], bwB[nt], aB[mt][nt], 0, 0, 0);
        }
    }
    #pragma unroll
    for (int mt = 0; mt < 4; mt++)
      #pragma unroll
      for (int nt = 0; nt < 2; nt++) {
        int c = cp * 128 + wv * 32 + nt * 16 + lc;
        #pragma unroll
        for (int r = 0; r < 4; r++) {
          int n = n0 + mt * 16 + qd * 4 + r;
          z1b[(size_t)n * 256 + c] = (__bf16)aA[mt][nt][r];
          z2b[(size_t)n * 256 + c] = (__bf16)aB[mt][nt][r];
        }
      }
  }
}

// ---------------- fused message kernel v13: v10 + XCD-chunked block swizzle ----------------
// v10 core (round-4, measured 64.1us). Edges are sorted by dst, so consecutive
// blocks share dst nodes -> their z2[dst] rows and aggH atomic lines. Default
// dispatch round-robins consecutive blocks over the 8 non-coherent XCD L2s,
// bouncing those lines. Chunked swizzle gives each XCD a contiguous 64K-edge
// range: per-XCD aggH slice ~2MB + z2 slice ~1MB, both L2-resident.
__global__ __launch_bounds__(256, 8) void msg_mfma_kernel(
    const __bf16* __restrict__ z1b, const __bf16* __restrict__ z2b,
    const __bf16* __restrict__ efb,
    const int* __restrict__ esrc, const int* __restrict__ edst,
    const __bf16* __restrict__ B2c, float* __restrict__ aggH)
{
  __shared__ __align__(16) __bf16 s_hT[128][68];   // 17408 B
  __shared__ __align__(16) __bf16 s_ef[TE][16];    // 2048 B
  __shared__ int s_src[TE];
  __shared__ int s_dst[TE];
  __shared__ unsigned int s_mask[2];

  int tid = threadIdx.x;
  // XCD-chunked bijective swizzle (gridDim.x = 8192, divisible by 8)
  const int cpx = (NEDGES / TE) >> 3;            // 1024 blocks per XCD chunk
  int wg = (blockIdx.x & 7) * cpx + (blockIdx.x >> 3);
  int e0 = wg * TE;

  if (tid < TE) {
    int d = edst[e0 + tid];
    s_dst[tid] = d;
    int dp = (tid == 0) ? (d ^ 1) : edst[e0 + tid - 1];
    unsigned long long mb = __ballot(d != dp);
    if (tid == 0) { s_mask[0] = (unsigned int)mb; s_mask[1] = (unsigned int)(mb >> 32); }
  } else if (tid < 2 * TE) {
    s_src[tid - TE] = esrc[e0 + tid - TE];
  }
  {
    int e = tid >> 2, t4 = tid & 3;
    if (t4 < 2)
      *(bf16x8*)&s_ef[e][t4 * 8] =
          *(const bf16x8*)(efb + (size_t)(e0 + e) * 16 + t4 * 8);
  }
  __syncthreads();

  const int wv = tid >> 6, ln = tid & 63, lc = ln & 15, qd = ln >> 4;

  // identity B fragment: C[e][c] = A[e][c] + A[e][c+16] (z1[src]+z2[dst])
  bf16x8 bI;
  #pragma unroll
  for (int j = 0; j < 8; j++)
    bI[j] = (__bf16)((lc == (qd & 1) * 8 + j) ? 1.0f : 0.0f);

  // z row pointers: qd<2 supplies z1[src] k-halves, qd>=2 z2[dst]
  const __bf16* pz[4];
  #pragma unroll
  for (int mt = 0; mt < 4; mt++) {
    int m = mt * 16 + lc;
    int row = (qd < 2) ? s_src[m] : s_dst[m];
    pz[mt] = ((qd < 2) ? z1b : z2b) + (size_t)row * 256 + (qd & 1) * 8;
  }

  // ef A-fragments (rows = edges), reused across both passes
  bf16x8 aef[4];
  #pragma unroll
  for (int mt = 0; mt < 4; mt++)
    aef[mt] = *(const bf16x8*)&s_ef[mt * 16 + lc][(qd & 1) * 8];

  // scan-role constants: 2 threads per column, 32 rows each
  const int sj = tid & 127;
  const int srow0 = (tid >> 7) * 32;
  const unsigned int smask = __builtin_amdgcn_readfirstlane(s_mask[tid >> 7]);

  #pragma unroll
  for (int hf = 0; hf < 2; hf++) {
    if (hf) __syncthreads();   // protect s_hT until previous scan done

    #pragma unroll
    for (int nt = 0; nt < 2; nt++) {
      const int cb = hf * 128 + wv * 32 + nt * 16;
      bf16x8 bw = *(const bf16x8*)(B2c + (size_t)(cb + lc) * 32 + qd * 8);
      #pragma unroll
      for (int mt = 0; mt < 4; mt++) {
        bf16x8 az = *(const bf16x8*)(pz[mt] + cb);
        f32x4 z; z[0] = 0.f; z[1] = 0.f; z[2] = 0.f; z[3] = 0.f;
        f32x4 acc = __builtin_amdgcn_mfma_f32_16x16x32_bf16(az, bI, z, 0, 0, 0);
        acc = __builtin_amdgcn_mfma_f32_16x16x32_bf16(aef[mt], bw, acc, 0, 0, 0);
        bf16x4 pv;
        pv[0] = (__bf16)silu_f(acc[0]); pv[1] = (__bf16)silu_f(acc[1]);
        pv[2] = (__bf16)silu_f(acc[2]); pv[3] = (__bf16)silu_f(acc[3]);
        *(bf16x4*)&s_hT[wv * 32 + nt * 16 + lc][mt * 16 + qd * 4] = pv;
      }
    }
    __syncthreads();

    // scan: 256 threads x (1 column half): col sj, rows [srow0, srow0+32)
    // 4 rows per iter; uniform fast path when no boundary in the chunk.
    {
      const int gcol = hf * 128 + sj;
      float acc = 0.0f;
      int cur = s_dst[srow0];
      #pragma unroll
      for (int i = 0; i < 32; i += 4) {
        unsigned int bm = (smask >> i) & 0xFu;
        if (i == 0) bm &= 0xEu;   // never flush before the window's first row
        bf16x4 p = *(const bf16x4*)&s_hT[sj][srow0 + i];
        if (bm == 0u) {
          acc += ((float)p[0] + (float)p[1]) + ((float)p[2] + (float)p[3]);
        } else {
          #pragma unroll
          for (int r = 0; r < 4; r++) {
            if ((bm >> r) & 1u) {
              atomicAdd(&aggH[(size_t)cur * 256 + gcol], acc);
              acc = 0.0f; cur = s_dst[srow0 + i + r];
            }
            acc += (float)p[r];
          }
        }
      }
      atomicAdd(&aggH[(size_t)cur * 256 + gcol], acc);
    }
  }
}

// ---------------- fused node update MLP v4 (round-4 verbatim, proven) ----------------
__global__ __launch_bounds__(512, 2) void upd_mfma_kernel(
    float* __restrict__ h, __bf16* __restrict__ hb,
    float* __restrict__ aggH, const float* __restrict__ degf,
    const __bf16* __restrict__ uW1ft, const float* __restrict__ b1,
    const float* __restrict__ b2u,
    const __bf16* __restrict__ uW2t, const float* __restrict__ b2,
    int do_z, const float* __restrict__ nb1,
    const __bf16* __restrict__ nW1at, const __bf16* __restrict__ nW1bt,
    __bf16* __restrict__ z1b, __bf16* __restrict__ z2b)
{
  __shared__ __bf16 s_u[64][392];    // [h(128) | agg(256)] + 8 pad
  __shared__ __bf16 s_uh[64][264];   // 256 hidden cols + 8 pad
  int tid = threadIdx.x, n0 = blockIdx.x * 64;
  {
    int n = tid >> 3, t8 = tid & 7;  // 8 threads per node
    const bf16x8* hr = (const bf16x8*)(hb + (size_t)(n0 + n) * 128);
    #pragma unroll
    for (int i = 0; i < 2; i++)
      *(bf16x8*)&s_u[n][t8 * 8 + 64 * i] = hr[t8 + 8 * i];
    const float* sr = aggH + (size_t)(n0 + n) * 256;
    #pragma unroll
    for (int i = 0; i < 4; i++) {
      int col = t8 * 8 + i * 64;
      float4 a = *(const float4*)(sr + col);
      float4 b = *(const float4*)(sr + col + 4);
      bf16x8 o;
      o[0] = (__bf16)a.x; o[1] = (__bf16)a.y; o[2] = (__bf16)a.z; o[3] = (__bf16)a.w;
      o[4] = (__bf16)b.x; o[5] = (__bf16)b.y; o[6] = (__bf16)b.z; o[7] = (__bf16)b.w;
      *(bf16x8*)&s_u[n][128 + col] = o;
    }
  }
  __syncthreads();
  const int wv = tid >> 6, ln = tid & 63, lc = ln & 15, qd = ln >> 4;  // wv 0..7

  float dg[4][4];
  #pragma unroll
  for (int mt = 0; mt < 4; mt++)
    #pragma unroll
    for (int r = 0; r < 4; r++)
      dg[mt][r] = degf[n0 + mt * 16 + qd * 4 + r];

  // ---- GEMM1: K=384, wave owns cols wv*32 + nt*16 + lc ----
  {
    f32x4 acc1[4][2];
    #pragma unroll
    for (int nt = 0; nt < 2; nt++) {
      int c = wv * 32 + nt * 16 + lc;
      float bv = b1[c];
      float b2uv = b2u[c];
      #pragma unroll
      for (int mt = 0; mt < 4; mt++)
        #pragma unroll
        for (int r = 0; r < 4; r++)
          acc1[mt][nt][r] = bv + dg[mt][r] * b2uv;
    }
    #pragma unroll
    for (int kt = 0; kt < 12; kt++) {
      bf16x8 af[4];
      #pragma unroll
      for (int mt = 0; mt < 4; mt++)
        af[mt] = *(const bf16x8*)&s_u[mt * 16 + lc][kt * 32 + qd * 8];
      bf16x8 bw[2];
      #pragma unroll
      for (int nt = 0; nt < 2; nt++)
        bw[nt] = *(const bf16x8*)(uW1ft +
                 (size_t)(wv * 32 + nt * 16 + lc) * 384 + kt * 32 + qd * 8);
      #pragma unroll
      for (int mt = 0; mt < 4; mt++)
        #pragma unroll
        for (int nt = 0; nt < 2; nt++)
          acc1[mt][nt] = __builtin_amdgcn_mfma_f32_16x16x32_bf16(af[mt], bw[nt], acc1[mt][nt], 0, 0, 0);
    }
    #pragma unroll
    for (int mt = 0; mt < 4; mt++)
      #pragma unroll
      for (int nt = 0; nt < 2; nt++) {
        int cc = wv * 32 + nt * 16 + lc;
        #pragma unroll
        for (int r = 0; r < 4; r++)
          s_uh[mt * 16 + qd * 4 + r][cc] = (__bf16)silu_f(acc1[mt][nt][r]);
      }
  }
  __syncthreads();

  // ---- GEMM2: K=256, wave owns output cols ow = wv*16 + lc ----
  const int ow = wv * 16 + lc;
  f32x4 acc2[4];
  {
    float bv = b2[ow];
    #pragma unroll
    for (int mt = 0; mt < 4; mt++) {
      acc2[mt][0] = bv; acc2[mt][1] = bv; acc2[mt][2] = bv; acc2[mt][3] = bv;
    }
  }
  #pragma unroll
  for (int kt = 0; kt < 8; kt++) {
    bf16x8 a2[4];
    #pragma unroll
    for (int mt = 0; mt < 4; mt++)
      a2[mt] = *(const bf16x8*)&s_uh[mt * 16 + lc][kt * 32 + qd * 8];
    bf16x8 b2w = *(const bf16x8*)(uW2t + (size_t)ow * 256 + kt * 32 + qd * 8);
    #pragma unroll
    for (int mt = 0; mt < 4; mt++)
      acc2[mt] = __builtin_amdgcn_mfma_f32_16x16x32_bf16(a2[mt], b2w, acc2[mt], 0, 0, 0);
  }

  // residual epilogue
  #pragma unroll
  for (int mt = 0; mt < 4; mt++)
    #pragma unroll
    for (int r = 0; r < 4; r++) {
      int n = n0 + mt * 16 + qd * 4 + r;
      float v = h[(size_t)n * 128 + ow] + acc2[mt][r];
      h[(size_t)n * 128 + ow] = v;
      hb[(size_t)n * 128 + ow] = (__bf16)v;
    }

  // ---- fused zprep for next layer ----
  if (do_z) {
    __syncthreads();
    {
      float4 zz = make_float4(0.f, 0.f, 0.f, 0.f);
      float4* ap = (float4*)(aggH + (size_t)n0 * 256);
      for (int i = tid; i < 64 * 256 / 4; i += 512) ap[i] = zz;
      int n = tid >> 3, t8 = tid & 7;
      const bf16x8* hr = (const bf16x8*)(hb + (size_t)(n0 + n) * 128);
      #pragma unroll
      for (int i = 0; i < 2; i++)
        *(bf16x8*)&s_u[n][t8 * 8 + 64 * i] = hr[t8 + 8 * i];
    }
    __syncthreads();
    f32x4 aA[4][2], aB[4][2];
    #pragma unroll
    for (int nt = 0; nt < 2; nt++) {
      float bv = nb1[wv * 32 + nt * 16 + lc];
      #pragma unroll
      for (int mt = 0; mt < 4; mt++) {
        aA[mt][nt][0] = 0.f; aA[mt][nt][1] = 0.f;
        aA[mt][nt][2] = 0.f; aA[mt][nt][3] = 0.f;
        aB[mt][nt][0] = bv; aB[mt][nt][1] = bv;
        aB[mt][nt][2] = bv; aB[mt][nt][3] = bv;
      }
    }
    #pragma unroll
    for (int kt = 0; kt < 4; kt++) {
      bf16x8 af[4];
      #pragma unroll
      for (int mt = 0; mt < 4; mt++)
        af[mt] = *(const bf16x8*)&s_u[mt * 16 + lc][kt * 32 + qd * 8];
      bf16x8 bwA[2], bwB[2];
      #pragma unroll
      for (int nt = 0; nt < 2; nt++) {
        int c = wv * 32 + nt * 16 + lc;
        bwA[nt] = *(const bf16x8*)(nW1at + (size_t)c * 128 + kt * 32 + qd * 8);
        bwB[nt] = *(const bf16x8*)(nW1bt + (size_t)c * 128 + kt * 32 + qd * 8);
      }
      #pragma unroll
      for (int mt = 0; mt < 4; mt++)
        #pragma unroll
        for (int nt = 0; nt < 2; nt++) {
          aA[mt][nt] = __builtin_amdgcn_mfma_f32_16x16x32_bf16(af[mt], bwA[nt], aA[mt][nt], 0, 0, 0);
          aB[mt][nt] = __builtin_amdgcn_mfma_f32_16x16x32_bf16(af[mt], bwB[nt], aB[mt][nt], 0, 0, 0);
        }
    }
    #pragma unroll
    for (int mt = 0; mt < 4; mt++)
      #pragma unroll
      for (int nt = 0; nt < 2; nt++) {
        int c = wv * 32 + nt * 16 + lc;
        #pragma unroll
        for (int r = 0; r < 4; r++) {
          int n = n0 + mt * 16 + qd * 4 + r;
          z1b[(size_t)n * 256 + c] = (__bf16)aA[mt][nt][r];
          z2b[(size_t)n * 256 + c] = (__bf16)aB[mt][nt][r];
        }
      }
  }
}

// ---------------- readout ----------------
__global__ __launch_bounds__(128) void readout_sum_kernel(
    const float* __restrict__ h, const int* __restrict__ batch,
    float* __restrict__ gsum, float* __restrict__ gcnt)
{
  int j = threadIdx.x;
  int n0 = blockIdx.x * 128;
  float acc = 0.f, cacc = 0.f;
  int cur = batch[n0];
  for (int i = 0; i < 128; i++) {
    int b = batch[n0 + i];
    if (b != cur) {
      atomicAdd(&gsum[cur * 128 + j], acc);
      if (j == 0) atomicAdd(&gcnt[cur], cacc);
      acc = 0.f; cacc = 0.f; cur = b;
    }
    acc += h[(size_t)(n0 + i) * 128 + j];
    cacc += 1.f;
  }
  atomicAdd(&gsum[cur * 128 + j], acc);
  if (j == 0) atomicAdd(&gcnt[cur], cacc);
}

__global__ __launch_bounds__(256) void readout_mlp_kernel(
    const float* __restrict__ gsum, const float* __restrict__ gcnt,
    const float* __restrict__ W1, const float* __restrict__ b1,
    const float* __restrict__ W2, const float* __restrict__ b2,
    float* __restrict__ out)
{
  __shared__ float g[8][128];
  __shared__ float hid[8][256];
  int tid = threadIdx.x;
  for (int i = tid; i < 8 * 128; i += 256) {
    int b = i >> 7, c = i & 127;
    g[b][c] = gsum[i] / fmaxf(gcnt[b], 1.0f);
  }
  __syncthreads();
  {
    float bb = b1[tid];
    float a[8];
    #pragma unroll
    for (int b = 0; b < 8; b++) a[b] = bb;
    for (int k = 0; k < 128; k++) {
      float w = W1[k * 256 + tid];
      #pragma unroll
      for (int b = 0; b < 8; b++) a[b] += g[b][k] * w;
    }
    #pragma unroll
    for (int b = 0; b < 8; b++) hid[b][tid] = silu_f(a[b]);
  }
  __syncthreads();
  int j = tid & 63, bg = tid >> 6;
  float a0 = b2[j], a1 = b2[j];
  for (int k = 0; k < 256; k++) {
    float w = W2[k * 64 + j];
    a0 += hid[bg * 2 + 0][k] * w;
    a1 += hid[bg * 2 + 1][k] * w;
  }
  out[(bg * 2 + 0) * 64 + j] = a0;
  out[(bg * 2 + 1) * 64 + j] = a1;
}

extern "C" void kernel_launch(void* const* d_in, const int* in_sizes, int n_in,
                              void* d_out, int out_size, void* d_ws, size_t ws_size,
                              hipStream_t stream) {
  const float* pos   = (const float*)d_in[0];
  const float* xfeat = (const float*)d_in[1];
  const int*   eidx  = (const int*)d_in[2];
  const int*   batch = (const int*)d_in[3];
  const float* eW1 = (const float*)d_in[4];
  const float* eb1 = (const float*)d_in[5];
  const float* eW2 = (const float*)d_in[6];
  const float* eb2 = (const float*)d_in[7];
  const float* mW1 = (const float*)d_in[8];
  const float* mb1 = (const float*)d_in[9];
  const float* mW2 = (const float*)d_in[10];
  const float* mb2 = (const float*)d_in[11];
  const float* uW1 = (const float*)d_in[12];
  const float* ub1 = (const float*)d_in[13];
  const float* uW2 = (const float*)d_in[14];
  const float* ub2 = (const float*)d_in[15];
  const float* rW1 = (const float*)d_in[16];
  const float* rb1 = (const float*)d_in[17];
  const float* rW2 = (const float*)d_in[18];
  const float* rb2 = (const float*)d_in[19];

  const int* srcI = eidx;
  const int* dstI = eidx + NEDGES;

  char* base = (char*)d_ws;
  float* h    = (float*)base;  base += (size_t)NATOMS * 128 * 4;
  float* aggH = (float*)base;  base += (size_t)NATOMS * 256 * 4;
  __bf16* z1b = (__bf16*)base; base += (size_t)NATOMS * 256 * 2;
  __bf16* z2b = (__bf16*)base; base += (size_t)NATOMS * 256 * 2;
  __bf16* hb  = (__bf16*)base; base += (size_t)NATOMS * 128 * 2;
  __bf16* efb = (__bf16*)base; base += (size_t)NEDGES * 16 * 2;
  __bf16* W1at = (__bf16*)base; base += (size_t)NLAYERS * 256 * 128 * 2;
  __bf16* W1bt = (__bf16*)base; base += (size_t)NLAYERS * 256 * 128 * 2;
  __bf16* B2c  = (__bf16*)base; base += (size_t)NLAYERS * 256 * 32 * 2;
  __bf16* uW1ft = (__bf16*)base; base += (size_t)NLAYERS * 256 * 384 * 2;
  __bf16* uW2t = (__bf16*)base; base += (size_t)NLAYERS * 128 * 256 * 2;
  float* b2u  = (float*)base;  base += (size_t)NLAYERS * 256 * 4;
  float* degf = (float*)base;  base += (size_t)NATOMS * 4;
  float* gsum = (float*)base;  base += 8 * 128 * 4;
  float* gcnt = (float*)base;  base += 8 * 4;
  int* counts = (int*)base;    base += (size_t)NATOMS * 4;
  int* cursor = (int*)base;    base += (size_t)NATOMS * 4;
  int* esrc   = (int*)base;    base += (size_t)NEDGES * 4;
  int* edst   = (int*)base;    base += (size_t)NEDGES * 4;

  // counts must be zeroed before front_kernel's hist section
  hipMemsetAsync(counts, 0, NATOMS * sizeof(int), stream);

  // merged front: weight prep + dst histogram + embedding
  front_kernel<<<NB_PREP + NB_HIST + NB_EMB, 256, 0, stream>>>(
      mW1, mW2, uW1, uW2, mb2, W1at, W1bt, B2c, uW1ft, uW2t, b2u,
      dstI, counts, xfeat, eW1, eb1, eW2, eb2, h, hb);

  scan_kernel<<<1, 1024, 0, stream>>>(counts, cursor, degf);
  scatter_rbf_kernel<<<NEDGES / 256, 256, 0, stream>>>(
      srcI, dstI, cursor, pos, esrc, edst, efb);

  // zprep for layer 0 (also zeros aggH)
  zprep_kernel<<<NATOMS / 64, 256, 0, stream>>>(
      hb, mb1, W1at, W1bt, z1b, z2b, aggH);

  for (int l = 0; l < NLAYERS; l++) {
    int ln = (l < NLAYERS - 1) ? (l + 1) : l;
    msg_mfma_kernel<<<NEDGES / TE, 256, 0, stream>>>(
        z1b, z2b, efb, esrc, edst,
        B2c + (size_t)l * 256 * 32, aggH);
    upd_mfma_kernel<<<NATOMS / 64, 512, 0, stream>>>(
        h, hb, aggH, degf,
        uW1ft + (size_t)l * 256 * 384, ub1 + (size_t)l * 256,
        b2u + (size_t)l * 256,
        uW2t + (size_t)l * 128 * 256, ub2 + (size_t)l * 128,
        (l < NLAYERS - 1) ? 1 : 0,
        mb1 + (size_t)ln * 256,
        W1at + (size_t)ln * 256 * 128, W1bt + (size_t)ln * 256 * 128,
        z1b, z2b);
  }

  hipMemsetAsync(gsum, 0, (8 * 128 + 8) * sizeof(float), stream);
  readout_sum_kernel<<<NATOMS / 128, 128, 0, stream>>>(h, batch, gsum, gcnt);
  readout_mlp_kernel<<<1, 256, 0, stream>>>(gsum, gcnt, rW1, rb1, rW2, rb2,
                                            (float*)d_out);
}

// Round 10
// 572.399 us; speedup vs baseline: 2.2425x; 1.0183x over previous
//
#include <hip/hip_runtime.h>
#include <math.h>

#define NATOMS 16384
#define NEDGES 524288
#define NLAYERS 4
#define TE 64      // edges per block in msg kernel

typedef __bf16 bf16x8 __attribute__((ext_vector_type(8)));
typedef __bf16 bf16x4 __attribute__((ext_vector_type(4)));
typedef __bf16 bf16x2 __attribute__((ext_vector_type(2)));
typedef float f32x4 __attribute__((ext_vector_type(4)));

// fast silu: x * rcp(1+exp(-x))
__device__ __forceinline__ float silu_f(float x) {
  return x * __builtin_amdgcn_rcpf(1.0f + __expf(-x));
}

// ---------------- CSR preprocessing (shfl scan: 2 barriers, was 20) ----------------
__global__ __launch_bounds__(1024) void scan_kernel(
    const int* __restrict__ counts, int* __restrict__ cursor,
    float* __restrict__ degf)
{
  __shared__ int s_ws[16];
  int tid = threadIdx.x;
  int v[16];
  {
    const int4* cp = (const int4*)(counts + tid * 16);
    int4 a = cp[0], b = cp[1], c = cp[2], d = cp[3];
    v[0]=a.x; v[1]=a.y; v[2]=a.z; v[3]=a.w;
    v[4]=b.x; v[5]=b.y; v[6]=b.z; v[7]=b.w;
    v[8]=c.x; v[9]=c.y; v[10]=c.z; v[11]=c.w;
    v[12]=d.x; v[13]=d.y; v[14]=d.z; v[15]=d.w;
  }
  int tot = 0;
  #pragma unroll
  for (int i = 0; i < 16; i++) tot += v[i];

  int lane = tid & 63, wv = tid >> 6;
  int sc = tot;   // inclusive wave scan
  #pragma unroll
  for (int off = 1; off < 64; off <<= 1) {
    int t = __shfl_up(sc, off, 64);
    if (lane >= off) sc += t;
  }
  if (lane == 63) s_ws[wv] = sc;
  __syncthreads();
  if (wv == 0 && lane < 16) {
    int w = s_ws[lane];
    #pragma unroll
    for (int off = 1; off < 16; off <<= 1) {
      int t = __shfl_up(w, off, 64);
      if (lane >= off) w += t;
    }
    s_ws[lane] = w;   // inclusive wave-sum scan
  }
  __syncthreads();
  int wbase = (wv == 0) ? 0 : s_ws[wv - 1];
  int run = wbase + sc - tot;   // exclusive prefix for this thread
  #pragma unroll
  for (int i = 0; i < 16; i++) {
    cursor[tid * 16 + i] = run;
    degf[tid * 16 + i] = (float)v[i];
    run += v[i];
  }
}

// ---------------- merged front kernel v3 ----------------
// prep: LDS-tiled 64x64 transposes, 16-row-slab fusion GEMM, 32-node embed
// blocks, + one block zeroing gsum/gcnt (replaces a separate memset launch).
#define NB_PL   50
#define NB_PREP (NB_PL * NLAYERS)
#define NB_HIST (NEDGES / 256)
#define NB_EMB  (NATOMS / 32)

__global__ __launch_bounds__(256) void front_kernel(
    const float* __restrict__ mW1, const float* __restrict__ mW2,
    const float* __restrict__ uW1, const float* __restrict__ uW2,
    const float* __restrict__ mb2,
    __bf16* __restrict__ W1at, __bf16* __restrict__ W1bt,
    __bf16* __restrict__ B2c, __bf16* __restrict__ uW1ft,
    __bf16* __restrict__ uW2t, float* __restrict__ b2u,
    const int* __restrict__ dstI, int* __restrict__ counts,
    const float* __restrict__ x, const float* __restrict__ eW1,
    const float* __restrict__ eb1, const float* __restrict__ eW2,
    const float* __restrict__ eb2, float* __restrict__ h,
    __bf16* __restrict__ hb, float* __restrict__ gsum)
{
  __shared__ __align__(16) char smem[19712];
  int bxf = blockIdx.x, tid = threadIdx.x;

  if (bxf < NB_PREP) {
    int l = bxf / NB_PL;
    int bx = bxf - l * NB_PL;
    if (bx < 16) {
      // W1at / W1bt: transpose 64x64 tiles of mW1 rows [0,256)
      float (*tile)[65] = (float(*)[65])smem;
      int tt = bx & 7;
      int row0 = ((tt >> 2) * 64) + ((bx < 8) ? 0 : 128);   // source k-row
      int col0 = (tt & 3) * 64;                             // source col (c)
      const float* Sp = mW1 + (size_t)l * (272 * 256) + (size_t)row0 * 256 + col0;
      __bf16* Dq = ((bx < 8) ? W1at : W1bt) + (size_t)l * (256 * 128);
      int dro = (bx < 8) ? row0 : row0 - 128;
      int c = tid & 63, r4 = tid >> 6;
      #pragma unroll
      for (int i = 0; i < 16; i++)
        tile[r4 + i * 4][c] = Sp[(size_t)(r4 + i * 4) * 256 + c];
      __syncthreads();
      #pragma unroll
      for (int i = 0; i < 16; i++) {
        int dr = r4 + i * 4;
        Dq[(size_t)(col0 + dr) * 128 + dro + c] = (__bf16)tile[c][dr];
      }
    } else if (bx == 16) {
      // B2c: rows 256..271 of mW1 -> [c][k] with zero pad to k=32
      float (*t3)[257] = (float(*)[257])smem;
      const float* Sp = mW1 + (size_t)l * (272 * 256) + 256 * 256;
      #pragma unroll
      for (int i = 0; i < 16; i++) t3[i][tid] = Sp[i * 256 + tid];
      __syncthreads();
      __bf16* Dp = B2c + (size_t)l * (256 * 32) + (size_t)tid * 32;
      #pragma unroll
      for (int g = 0; g < 4; g++) {
        bf16x8 o;
        #pragma unroll
        for (int j2 = 0; j2 < 8; j2++) {
          int k = g * 8 + j2;
          o[j2] = (__bf16)((k < 16) ? t3[k][tid] : 0.0f);
        }
        *(bf16x8*)(Dp + g * 8) = o;
      }
    } else if (bx < 25) {
      // uW1ft copy part (k<128): transpose 64x64 tiles of uW1
      float (*tile)[65] = (float(*)[65])smem;
      int tt = bx - 17;
      int row0 = (tt >> 2) * 64;         // k
      int col0 = (tt & 3) * 64;          // n
      const float* Sp = uW1 + (size_t)l * 65536 + (size_t)row0 * 256 + col0;
      __bf16* Dq = uW1ft + (size_t)l * (256 * 384);
      int c = tid & 63, r4 = tid >> 6;
      #pragma unroll
      for (int i = 0; i < 16; i++)
        tile[r4 + i * 4][c] = Sp[(size_t)(r4 + i * 4) * 256 + c];
      __syncthreads();
      #pragma unroll
      for (int i = 0; i < 16; i++) {
        int dr = r4 + i * 4;
        Dq[(size_t)(col0 + dr) * 384 + row0 + c] = (__bf16)tile[c][dr];
      }
    } else if (bx < 41) {
      // fusion slab: F[r0+r][n] = sum_j mW2[r0+r][j] * uW1[128+j][n]
      float (*sA)[128] = (float(*)[128])smem;
      int r0 = (bx - 25) * 16;
      const float* Ap = mW2 + (size_t)(l * 256 + r0) * 128;
      #pragma unroll
      for (int i = 0; i < 8; i++) {
        int idx = i * 256 + tid;
        ((float*)smem)[idx] = Ap[idx];
      }
      __syncthreads();
      const float* Bp = uW1 + (size_t)l * 65536 + 128 * 256 + tid;
      float acc[16];
      #pragma unroll
      for (int r = 0; r < 16; r++) acc[r] = 0.0f;
      for (int k = 0; k < 128; k++) {
        float b = Bp[(size_t)k * 256];
        #pragma unroll
        for (int r = 0; r < 16; r++) acc[r] += sA[r][k] * b;
      }
      __bf16* Dp = uW1ft + (size_t)l * (256 * 384) + (size_t)tid * 384 + 128 + r0;
      bf16x8 o0, o1;
      #pragma unroll
      for (int r = 0; r < 8; r++) { o0[r] = (__bf16)acc[r]; o1[r] = (__bf16)acc[8 + r]; }
      *(bf16x8*)Dp = o0;
      *(bf16x8*)(Dp + 8) = o1;
    } else if (bx < 49) {
      // uW2t: transpose 64x64 tiles of uW2 (256x128)
      float (*tile)[65] = (float(*)[65])smem;
      int tt = bx - 41;
      int row0 = (tt >> 1) * 64;     // k in [0,256)
      int col0 = (tt & 1) * 64;      // n in [0,128)
      const float* Sp = uW2 + (size_t)l * (256 * 128) + (size_t)row0 * 128 + col0;
      __bf16* Dq = uW2t + (size_t)l * (128 * 256);
      int c = tid & 63, r4 = tid >> 6;
      #pragma unroll
      for (int i = 0; i < 16; i++)
        tile[r4 + i * 4][c] = Sp[(size_t)(r4 + i * 4) * 128 + c];
      __syncthreads();
      #pragma unroll
      for (int i = 0; i < 16; i++) {
        int dr = r4 + i * 4;
        Dq[(size_t)(col0 + dr) * 256 + row0 + c] = (__bf16)tile[c][dr];
      }
    } else {
      // b2u[c] = sum_j mb2[j] * uW1[128+j][c]
      int cc = tid;
      float acc = 0.0f;
      for (int j2 = 0; j2 < 128; j2++)
        acc += mb2[l * 128 + j2] * uW1[(size_t)l * 65536 + (size_t)(128 + j2) * 256 + cc];
      b2u[l * 256 + cc] = acc;
    }
  } else if (bxf < NB_PREP + NB_HIST) {
    int e = (bxf - NB_PREP) * 256 + tid;
    atomicAdd(&counts[dstI[e]], 1);
  } else if (bxf < NB_PREP + NB_HIST + NB_EMB) {
    // embedding: 32 nodes per block, 16 accumulators per thread
    int nb = bxf - (NB_PREP + NB_HIST);
    int n0e = nb * 32;
    float* xsf = (float*)smem;                               // [32][26]
    float (*hid2)[128] = (float(*)[128])(smem + 32 * 26 * 4);
    for (int i = tid; i < 32 * 26; i += 256)
      xsf[i] = x[(size_t)n0e * 26 + i];
    __syncthreads();
    int j = tid & 127, ns = tid >> 7;
    float a1[16];
    {
      float bb = eb1[j];
      #pragma unroll
      for (int i = 0; i < 16; i++) a1[i] = bb;
    }
    for (int k = 0; k < 26; k++) {
      float w = eW1[k * 128 + j];
      #pragma unroll
      for (int i = 0; i < 16; i++) a1[i] += xsf[(ns * 16 + i) * 26 + k] * w;
    }
    #pragma unroll
    for (int i = 0; i < 16; i++) hid2[ns * 16 + i][j] = silu_f(a1[i]);
    __syncthreads();
    float a2[16];
    {
      float bb = eb2[j];
      #pragma unroll
      for (int i = 0; i < 16; i++) a2[i] = bb;
    }
    for (int k = 0; k < 128; k++) {
      float w = eW2[k * 128 + j];
      #pragma unroll
      for (int i = 0; i < 16; i++) a2[i] += hid2[ns * 16 + i][k] * w;
    }
    #pragma unroll
    for (int i = 0; i < 16; i++) {
      int n = n0e + ns * 16 + i;
      h[(size_t)n * 128 + j] = a2[i];
      hb[(size_t)n * 128 + j] = (__bf16)a2[i];
    }
  } else {
    // zero gsum(1024) + gcnt(8) — replaces a memset launch
    for (int i = tid; i < 8 * 128 + 8; i += 256) gsum[i] = 0.0f;
  }
}

// ---------------- merged prep2: scatter_rbf (2048 blocks) + zprep (256 blocks) ----------------
// The two are mutually independent (both depend only on front+scan); role-split
// in one launch removes a gap and overlaps zprep's MFMA with scatter's trans ops.
#define NB_SCAT (NEDGES / 256)

__global__ __launch_bounds__(256) void prep2_kernel(
    const int* __restrict__ src, const int* __restrict__ dst,
    int* __restrict__ cursor, const float* __restrict__ pos,
    int* __restrict__ esrc, int* __restrict__ edst,
    __bf16* __restrict__ efb,
    const __bf16* __restrict__ hb, const float* __restrict__ b1,
    const __bf16* __restrict__ W1at, const __bf16* __restrict__ W1bt,
    __bf16* __restrict__ z1b, __bf16* __restrict__ z2b,
    float* __restrict__ aggH)
{
  __shared__ __bf16 s_n[64][136];
  int tid = threadIdx.x;

  if (blockIdx.x < NB_SCAT) {
    // ---- scatter + RBF ----
    int e = blockIdx.x * 256 + tid;
    int s = src[e], d = dst[e];
    int p = atomicAdd(&cursor[d], 1);
    esrc[p] = s;
    edst[p] = d;
    float dx = pos[d * 3 + 0] - pos[s * 3 + 0];
    float dy = pos[d * 3 + 1] - pos[s * 3 + 1];
    float dz = pos[d * 3 + 2] - pos[s * 3 + 2];
    float dist = sqrtf(dx * dx + dy * dy + dz * dz + 1e-12f);
    float env = (dist < 10.0f)
                    ? 0.5f * (cosf(3.14159265358979f * dist * 0.1f) + 1.0f)
                    : 0.0f;
    bf16x8 o0, o1;
    #pragma unroll
    for (int i = 0; i < 16; i++) {
      float c = (10.0f / 15.0f) * (float)i;
      float t = dist - c;
      float v = env * __expf(-t * t * 1.28f);
      if (i < 8) o0[i] = (__bf16)v; else o1[i - 8] = (__bf16)v;
    }
    *(bf16x8*)(efb + (size_t)p * 16 + 0) = o0;
    *(bf16x8*)(efb + (size_t)p * 16 + 8) = o1;
    return;
  }

  // ---- zprep (layer 0): z1b, z2b; zeros aggH ----
  int n0 = (blockIdx.x - NB_SCAT) * 64;
  {
    int n = tid >> 2, t4 = tid & 3;
    const bf16x8* hr = (const bf16x8*)(hb + (size_t)(n0 + n) * 128);
    #pragma unroll
    for (int i = 0; i < 4; i++)
      *(bf16x8*)&s_n[n][t4 * 8 + 32 * i] = hr[t4 + 4 * i];
  }
  {
    float4 zz = make_float4(0.f, 0.f, 0.f, 0.f);
    float4* ap = (float4*)(aggH + (size_t)n0 * 256);
    for (int i = tid; i < 64 * 256 / 4; i += 256) ap[i] = zz;
  }
  __syncthreads();
  const int wv = tid >> 6, ln = tid & 63, lc = ln & 15, qd = ln >> 4;
  for (int cp = 0; cp < 2; cp++) {
    f32x4 aA[4][2], aB[4][2];
    #pragma unroll
    for (int nt = 0; nt < 2; nt++) {
      float bv = b1[cp * 128 + wv * 32 + nt * 16 + lc];
      #pragma unroll
      for (int mt = 0; mt < 4; mt++) {
        aA[mt][nt][0] = 0.f; aA[mt][nt][1] = 0.f;
        aA[mt][nt][2] = 0.f; aA[mt][nt][3] = 0.f;
        aB[mt][nt][0] = bv; aB[mt][nt][1] = bv;
        aB[mt][nt][2] = bv; aB[mt][nt][3] = bv;
      }
    }
    #pragma unroll
    for (int kt = 0; kt < 4; kt++) {
      bf16x8 af[4];
      #pragma unroll
      for (int mt = 0; mt < 4; mt++)
        af[mt] = *(const bf16x8*)&s_n[mt * 16 + lc][kt * 32 + qd * 8];
      bf16x8 bwA[2], bwB[2];
      #pragma unroll
      for (int nt = 0; nt < 2; nt++) {
        int c = cp * 128 + wv * 32 + nt * 16 + lc;
        bwA[nt] = *(const bf16x8*)(W1at + (size_t)c * 128 + kt * 32 + qd * 8);
        bwB[nt] = *(const bf16x8*)(W1bt + (size_t)c * 128 + kt * 32 + qd * 8);
      }
      #pragma unroll
      for (int mt = 0; mt < 4; mt++)
        #pragma unroll
        for (int nt = 0; nt < 2; nt++) {
          aA[mt][nt] = __builtin_amdgcn_mfma_f32_16x16x32_bf16(af[mt], bwA[nt], aA[mt][nt], 0, 0, 0);
          aB[mt][nt] = __builtin_amdgcn_mfma_f32_16x16x32_bf16(af[mt], bwB[nt], aB[mt][nt], 0, 0, 0);
        }
    }
    #pragma unroll
    for (int mt = 0; mt < 4; mt++)
      #pragma unroll
      for (int nt = 0; nt < 2; nt++) {
        int c = cp * 128 + wv * 32 + nt * 16 + lc;
        #pragma unroll
        for (int r = 0; r < 4; r++) {
          int n = n0 + mt * 16 + qd * 4 + r;
          z1b[(size_t)n * 256 + c] = (__bf16)aA[mt][nt][r];
          z2b[(size_t)n * 256 + c] = (__bf16)aB[mt][nt][r];
        }
      }
  }
}

// ---------------- fused message kernel v13 (round-9, verified) ----------------
__global__ __launch_bounds__(256, 8) void msg_mfma_kernel(
    const __bf16* __restrict__ z1b, const __bf16* __restrict__ z2b,
    const __bf16* __restrict__ efb,
    const int* __restrict__ esrc, const int* __restrict__ edst,
    const __bf16* __restrict__ B2c, float* __restrict__ aggH)
{
  __shared__ __align__(16) __bf16 s_hT[128][68];   // 17408 B
  __shared__ __align__(16) __bf16 s_ef[TE][16];    // 2048 B
  __shared__ int s_src[TE];
  __shared__ int s_dst[TE];
  __shared__ unsigned int s_mask[2];

  int tid = threadIdx.x;
  // XCD-chunked bijective swizzle (gridDim.x = 8192, divisible by 8)
  const int cpx = (NEDGES / TE) >> 3;
  int wg = (blockIdx.x & 7) * cpx + (blockIdx.x >> 3);
  int e0 = wg * TE;

  if (tid < TE) {
    int d = edst[e0 + tid];
    s_dst[tid] = d;
    int dp = (tid == 0) ? (d ^ 1) : edst[e0 + tid - 1];
    unsigned long long mb = __ballot(d != dp);
    if (tid == 0) { s_mask[0] = (unsigned int)mb; s_mask[1] = (unsigned int)(mb >> 32); }
  } else if (tid < 2 * TE) {
    s_src[tid - TE] = esrc[e0 + tid - TE];
  }
  {
    int e = tid >> 2, t4 = tid & 3;
    if (t4 < 2)
      *(bf16x8*)&s_ef[e][t4 * 8] =
          *(const bf16x8*)(efb + (size_t)(e0 + e) * 16 + t4 * 8);
  }
  __syncthreads();

  const int wv = tid >> 6, ln = tid & 63, lc = ln & 15, qd = ln >> 4;

  // identity B fragment: C[e][c] = A[e][c] + A[e][c+16] (z1[src]+z2[dst])
  bf16x8 bI;
  #pragma unroll
  for (int j = 0; j < 8; j++)
    bI[j] = (__bf16)((lc == (qd & 1) * 8 + j) ? 1.0f : 0.0f);

  // z row pointers: qd<2 supplies z1[src] k-halves, qd>=2 z2[dst]
  const __bf16* pz[4];
  #pragma unroll
  for (int mt = 0; mt < 4; mt++) {
    int m = mt * 16 + lc;
    int row = (qd < 2) ? s_src[m] : s_dst[m];
    pz[mt] = ((qd < 2) ? z1b : z2b) + (size_t)row * 256 + (qd & 1) * 8;
  }

  // ef A-fragments (rows = edges), reused across both passes
  bf16x8 aef[4];
  #pragma unroll
  for (int mt = 0; mt < 4; mt++)
    aef[mt] = *(const bf16x8*)&s_ef[mt * 16 + lc][(qd & 1) * 8];

  // scan-role constants: 2 threads per column, 32 rows each
  const int sj = tid & 127;
  const int srow0 = (tid >> 7) * 32;
  const unsigned int smask = __builtin_amdgcn_readfirstlane(s_mask[tid >> 7]);

  #pragma unroll
  for (int hf = 0; hf < 2; hf++) {
    if (hf) __syncthreads();   // protect s_hT until previous scan done

    #pragma unroll
    for (int nt = 0; nt < 2; nt++) {
      const int cb = hf * 128 + wv * 32 + nt * 16;
      bf16x8 bw = *(const bf16x8*)(B2c + (size_t)(cb + lc) * 32 + qd * 8);
      #pragma unroll
      for (int mt = 0; mt < 4; mt++) {
        bf16x8 az = *(const bf16x8*)(pz[mt] + cb);
        f32x4 z; z[0] = 0.f; z[1] = 0.f; z[2] = 0.f; z[3] = 0.f;
        f32x4 acc = __builtin_amdgcn_mfma_f32_16x16x32_bf16(az, bI, z, 0, 0, 0);
        acc = __builtin_amdgcn_mfma_f32_16x16x32_bf16(aef[mt], bw, acc, 0, 0, 0);
        bf16x4 pv;
        pv[0] = (__bf16)silu_f(acc[0]); pv[1] = (__bf16)silu_f(acc[1]);
        pv[2] = (__bf16)silu_f(acc[2]); pv[3] = (__bf16)silu_f(acc[3]);
        *(bf16x4*)&s_hT[wv * 32 + nt * 16 + lc][mt * 16 + qd * 4] = pv;
      }
    }
    __syncthreads();

    // scan: 256 threads x (1 column half): col sj, rows [srow0, srow0+32)
    {
      const int gcol = hf * 128 + sj;
      float acc = 0.0f;
      int cur = s_dst[srow0];
      #pragma unroll
      for (int i = 0; i < 32; i += 4) {
        unsigned int bm = (smask >> i) & 0xFu;
        if (i == 0) bm &= 0xEu;   // never flush before the window's first row
        bf16x4 p = *(const bf16x4*)&s_hT[sj][srow0 + i];
        if (bm == 0u) {
          acc += ((float)p[0] + (float)p[1]) + ((float)p[2] + (float)p[3]);
        } else {
          #pragma unroll
          for (int r = 0; r < 4; r++) {
            if ((bm >> r) & 1u) {
              atomicAdd(&aggH[(size_t)cur * 256 + gcol], acc);
              acc = 0.0f; cur = s_dst[srow0 + i + r];
            }
            acc += (float)p[r];
          }
        }
      }
      atomicAdd(&aggH[(size_t)cur * 256 + gcol], acc);
    }
  }
}

// ---------------- fused node update MLP v4 (round-4 verbatim, proven) ----------------
__global__ __launch_bounds__(512, 2) void upd_mfma_kernel(
    float* __restrict__ h, __bf16* __restrict__ hb,
    float* __restrict__ aggH, const float* __restrict__ degf,
    const __bf16* __restrict__ uW1ft, const float* __restrict__ b1,
    const float* __restrict__ b2u,
    const __bf16* __restrict__ uW2t, const float* __restrict__ b2,
    int do_z, const float* __restrict__ nb1,
    const __bf16* __restrict__ nW1at, const __bf16* __restrict__ nW1bt,
    __bf16* __restrict__ z1b, __bf16* __restrict__ z2b)
{
  __shared__ __bf16 s_u[64][392];    // [h(128) | agg(256)] + 8 pad
  __shared__ __bf16 s_uh[64][264];   // 256 hidden cols + 8 pad
  int tid = threadIdx.x, n0 = blockIdx.x * 64;
  {
    int n = tid >> 3, t8 = tid & 7;  // 8 threads per node
    const bf16x8* hr = (const bf16x8*)(hb + (size_t)(n0 + n) * 128);
    #pragma unroll
    for (int i = 0; i < 2; i++)
      *(bf16x8*)&s_u[n][t8 * 8 + 64 * i] = hr[t8 + 8 * i];
    const float* sr = aggH + (size_t)(n0 + n) * 256;
    #pragma unroll
    for (int i = 0; i < 4; i++) {
      int col = t8 * 8 + i * 64;
      float4 a = *(const float4*)(sr + col);
      float4 b = *(const float4*)(sr + col + 4);
      bf16x8 o;
      o[0] = (__bf16)a.x; o[1] = (__bf16)a.y; o[2] = (__bf16)a.z; o[3] = (__bf16)a.w;
      o[4] = (__bf16)b.x; o[5] = (__bf16)b.y; o[6] = (__bf16)b.z; o[7] = (__bf16)b.w;
      *(bf16x8*)&s_u[n][128 + col] = o;
    }
  }
  __syncthreads();
  const int wv = tid >> 6, ln = tid & 63, lc = ln & 15, qd = ln >> 4;  // wv 0..7

  float dg[4][4];
  #pragma unroll
  for (int mt = 0; mt < 4; mt++)
    #pragma unroll
    for (int r = 0; r < 4; r++)
      dg[mt][r] = degf[n0 + mt * 16 + qd * 4 + r];

  // ---- GEMM1: K=384, wave owns cols wv*32 + nt*16 + lc ----
  {
    f32x4 acc1[4][2];
    #pragma unroll
    for (int nt = 0; nt < 2; nt++) {
      int c = wv * 32 + nt * 16 + lc;
      float bv = b1[c];
      float b2uv = b2u[c];
      #pragma unroll
      for (int mt = 0; mt < 4; mt++)
        #pragma unroll
        for (int r = 0; r < 4; r++)
          acc1[mt][nt][r] = bv + dg[mt][r] * b2uv;
    }
    #pragma unroll
    for (int kt = 0; kt < 12; kt++) {
      bf16x8 af[4];
      #pragma unroll
      for (int mt = 0; mt < 4; mt++)
        af[mt] = *(const bf16x8*)&s_u[mt * 16 + lc][kt * 32 + qd * 8];
      bf16x8 bw[2];
      #pragma unroll
      for (int nt = 0; nt < 2; nt++)
        bw[nt] = *(const bf16x8*)(uW1ft +
                 (size_t)(wv * 32 + nt * 16 + lc) * 384 + kt * 32 + qd * 8);
      #pragma unroll
      for (int mt = 0; mt < 4; mt++)
        #pragma unroll
        for (int nt = 0; nt < 2; nt++)
          acc1[mt][nt] = __builtin_amdgcn_mfma_f32_16x16x32_bf16(af[mt], bw[nt], acc1[mt][nt], 0, 0, 0);
    }
    #pragma unroll
    for (int mt = 0; mt < 4; mt++)
      #pragma unroll
      for (int nt = 0; nt < 2; nt++) {
        int cc = wv * 32 + nt * 16 + lc;
        #pragma unroll
        for (int r = 0; r < 4; r++)
          s_uh[mt * 16 + qd * 4 + r][cc] = (__bf16)silu_f(acc1[mt][nt][r]);
      }
  }
  __syncthreads();

  // ---- GEMM2: K=256, wave owns output cols ow = wv*16 + lc ----
  const int ow = wv * 16 + lc;
  f32x4 acc2[4];
  {
    float bv = b2[ow];
    #pragma unroll
    for (int mt = 0; mt < 4; mt++) {
      acc2[mt][0] = bv; acc2[mt][1] = bv; acc2[mt][2] = bv; acc2[mt][3] = bv;
    }
  }
  #pragma unroll
  for (int kt = 0; kt < 8; kt++) {
    bf16x8 a2[4];
    #pragma unroll
    for (int mt = 0; mt < 4; mt++)
      a2[mt] = *(const bf16x8*)&s_uh[mt * 16 + lc][kt * 32 + qd * 8];
    bf16x8 b2w = *(const bf16x8*)(uW2t + (size_t)ow * 256 + kt * 32 + qd * 8);
    #pragma unroll
    for (int mt = 0; mt < 4; mt++)
      acc2[mt] = __builtin_amdgcn_mfma_f32_16x16x32_bf16(a2[mt], b2w, acc2[mt], 0, 0, 0);
  }

  // residual epilogue
  #pragma unroll
  for (int mt = 0; mt < 4; mt++)
    #pragma unroll
    for (int r = 0; r < 4; r++) {
      int n = n0 + mt * 16 + qd * 4 + r;
      float v = h[(size_t)n * 128 + ow] + acc2[mt][r];
      h[(size_t)n * 128 + ow] = v;
      hb[(size_t)n * 128 + ow] = (__bf16)v;
    }

  // ---- fused zprep for next layer ----
  if (do_z) {
    __syncthreads();
    {
      float4 zz = make_float4(0.f, 0.f, 0.f, 0.f);
      float4* ap = (float4*)(aggH + (size_t)n0 * 256);
      for (int i = tid; i < 64 * 256 / 4; i += 512) ap[i] = zz;
      int n = tid >> 3, t8 = tid & 7;
      const bf16x8* hr = (const bf16x8*)(hb + (size_t)(n0 + n) * 128);
      #pragma unroll
      for (int i = 0; i < 2; i++)
        *(bf16x8*)&s_u[n][t8 * 8 + 64 * i] = hr[t8 + 8 * i];
    }
    __syncthreads();
    f32x4 aA[4][2], aB[4][2];
    #pragma unroll
    for (int nt = 0; nt < 2; nt++) {
      float bv = nb1[wv * 32 + nt * 16 + lc];
      #pragma unroll
      for (int mt = 0; mt < 4; mt++) {
        aA[mt][nt][0] = 0.f; aA[mt][nt][1] = 0.f;
        aA[mt][nt][2] = 0.f; aA[mt][nt][3] = 0.f;
        aB[mt][nt][0] = bv; aB[mt][nt][1] = bv;
        aB[mt][nt][2] = bv; aB[mt][nt][3] = bv;
      }
    }
    #pragma unroll
    for (int kt = 0; kt < 4; kt++) {
      bf16x8 af[4];
      #pragma unroll
      for (int mt = 0; mt < 4; mt++)
        af[mt] = *(const bf16x8*)&s_u[mt * 16 + lc][kt * 32 + qd * 8];
      bf16x8 bwA[2], bwB[2];
      #pragma unroll
      for (int nt = 0; nt < 2; nt++) {
        int c = wv * 32 + nt * 16 + lc;
        bwA[nt] = *(const bf16x8*)(nW1at + (size_t)c * 128 + kt * 32 + qd * 8);
        bwB[nt] = *(const bf16x8*)(nW1bt + (size_t)c * 128 + kt * 32 + qd * 8);
      }
      #pragma unroll
      for (int mt = 0; mt < 4; mt++)
        #pragma unroll
        for (int nt = 0; nt < 2; nt++) {
          aA[mt][nt] = __builtin_amdgcn_mfma_f32_16x16x32_bf16(af[mt], bwA[nt], aA[mt][nt], 0, 0, 0);
          aB[mt][nt] = __builtin_amdgcn_mfma_f32_16x16x32_bf16(af[mt], bwB[nt], aB[mt][nt], 0, 0, 0);
        }
    }
    #pragma unroll
    for (int mt = 0; mt < 4; mt++)
      #pragma unroll
      for (int nt = 0; nt < 2; nt++) {
        int c = wv * 32 + nt * 16 + lc;
        #pragma unroll
        for (int r = 0; r < 4; r++) {
          int n = n0 + mt * 16 + qd * 4 + r;
          z1b[(size_t)n * 256 + c] = (__bf16)aA[mt][nt][r];
          z2b[(size_t)n * 256 + c] = (__bf16)aB[mt][nt][r];
        }
      }
  }
}

// ---------------- readout ----------------
__global__ __launch_bounds__(128) void readout_sum_kernel(
    const float* __restrict__ h, const int* __restrict__ batch,
    float* __restrict__ gsum, float* __restrict__ gcnt)
{
  int j = threadIdx.x;
  int n0 = blockIdx.x * 128;
  float acc = 0.f, cacc = 0.f;
  int cur = batch[n0];
  for (int i = 0; i < 128; i++) {
    int b = batch[n0 + i];
    if (b != cur) {
      atomicAdd(&gsum[cur * 128 + j], acc);
      if (j == 0) atomicAdd(&gcnt[cur], cacc);
      acc = 0.f; cacc = 0.f; cur = b;
    }
    acc += h[(size_t)(n0 + i) * 128 + j];
    cacc += 1.f;
  }
  atomicAdd(&gsum[cur * 128 + j], acc);
  if (j == 0) atomicAdd(&gcnt[cur], cacc);
}

__global__ __launch_bounds__(256) void readout_mlp_kernel(
    const float* __restrict__ gsum, const float* __restrict__ gcnt,
    const float* __restrict__ W1, const float* __restrict__ b1,
    const float* __restrict__ W2, const float* __restrict__ b2,
    float* __restrict__ out)
{
  __shared__ float g[8][128];
  __shared__ float hid[8][256];
  int tid = threadIdx.x;
  for (int i = tid; i < 8 * 128; i += 256) {
    int b = i >> 7, c = i & 127;
    g[b][c] = gsum[i] / fmaxf(gcnt[b], 1.0f);
  }
  __syncthreads();
  {
    float bb = b1[tid];
    float a[8];
    #pragma unroll
    for (int b = 0; b < 8; b++) a[b] = bb;
    for (int k = 0; k < 128; k++) {
      float w = W1[k * 256 + tid];
      #pragma unroll
      for (int b = 0; b < 8; b++) a[b] += g[b][k] * w;
    }
    #pragma unroll
    for (int b = 0; b < 8; b++) hid[b][tid] = silu_f(a[b]);
  }
  __syncthreads();
  int j = tid & 63, bg = tid >> 6;
  float a0 = b2[j], a1 = b2[j];
  for (int k = 0; k < 256; k++) {
    float w = W2[k * 64 + j];
    a0 += hid[bg * 2 + 0][k] * w;
    a1 += hid[bg * 2 + 1][k] * w;
  }
  out[(bg * 2 + 0) * 64 + j] = a0;
  out[(bg * 2 + 1) * 64 + j] = a1;
}

extern "C" void kernel_launch(void* const* d_in, const int* in_sizes, int n_in,
                              void* d_out, int out_size, void* d_ws, size_t ws_size,
                              hipStream_t stream) {
  const float* pos   = (const float*)d_in[0];
  const float* xfeat = (const float*)d_in[1];
  const int*   eidx  = (const int*)d_in[2];
  const int*   batch = (const int*)d_in[3];
  const float* eW1 = (const float*)d_in[4];
  const float* eb1 = (const float*)d_in[5];
  const float* eW2 = (const float*)d_in[6];
  const float* eb2 = (const float*)d_in[7];
  const float* mW1 = (const float*)d_in[8];
  const float* mb1 = (const float*)d_in[9];
  const float* mW2 = (const float*)d_in[10];
  const float* mb2 = (const float*)d_in[11];
  const float* uW1 = (const float*)d_in[12];
  const float* ub1 = (const float*)d_in[13];
  const float* uW2 = (const float*)d_in[14];
  const float* ub2 = (const float*)d_in[15];
  const float* rW1 = (const float*)d_in[16];
  const float* rb1 = (const float*)d_in[17];
  const float* rW2 = (const float*)d_in[18];
  const float* rb2 = (const float*)d_in[19];

  const int* srcI = eidx;
  const int* dstI = eidx + NEDGES;

  char* base = (char*)d_ws;
  float* h    = (float*)base;  base += (size_t)NATOMS * 128 * 4;
  float* aggH = (float*)base;  base += (size_t)NATOMS * 256 * 4;
  __bf16* z1b = (__bf16*)base; base += (size_t)NATOMS * 256 * 2;
  __bf16* z2b = (__bf16*)base; base += (size_t)NATOMS * 256 * 2;
  __bf16* hb  = (__bf16*)base; base += (size_t)NATOMS * 128 * 2;
  __bf16* efb = (__bf16*)base; base += (size_t)NEDGES * 16 * 2;
  __bf16* W1at = (__bf16*)base; base += (size_t)NLAYERS * 256 * 128 * 2;
  __bf16* W1bt = (__bf16*)base; base += (size_t)NLAYERS * 256 * 128 * 2;
  __bf16* B2c  = (__bf16*)base; base += (size_t)NLAYERS * 256 * 32 * 2;
  __bf16* uW1ft = (__bf16*)base; base += (size_t)NLAYERS * 256 * 384 * 2;
  __bf16* uW2t = (__bf16*)base; base += (size_t)NLAYERS * 128 * 256 * 2;
  float* b2u  = (float*)base;  base += (size_t)NLAYERS * 256 * 4;
  float* degf = (float*)base;  base += (size_t)NATOMS * 4;
  float* gsum = (float*)base;  base += 8 * 128 * 4;
  float* gcnt = (float*)base;  base += 8 * 4;
  int* counts = (int*)base;    base += (size_t)NATOMS * 4;
  int* cursor = (int*)base;    base += (size_t)NATOMS * 4;
  int* esrc   = (int*)base;    base += (size_t)NEDGES * 4;
  int* edst   = (int*)base;    base += (size_t)NEDGES * 4;

  // counts must be zeroed before front_kernel's hist section
  hipMemsetAsync(counts, 0, NATOMS * sizeof(int), stream);

  // merged front: weight prep + dst histogram + embedding + gsum zero
  front_kernel<<<NB_PREP + NB_HIST + NB_EMB + 1, 256, 0, stream>>>(
      mW1, mW2, uW1, uW2, mb2, W1at, W1bt, B2c, uW1ft, uW2t, b2u,
      dstI, counts, xfeat, eW1, eb1, eW2, eb2, h, hb, gsum);

  scan_kernel<<<1, 1024, 0, stream>>>(counts, cursor, degf);

  // merged: scatter+RBF (2048 blocks) || zprep layer 0 (256 blocks, zeros aggH)
  prep2_kernel<<<NB_SCAT + NATOMS / 64, 256, 0, stream>>>(
      srcI, dstI, cursor, pos, esrc, edst, efb,
      hb, mb1, W1at, W1bt, z1b, z2b, aggH);

  for (int l = 0; l < NLAYERS; l++) {
    int ln = (l < NLAYERS - 1) ? (l + 1) : l;
    msg_mfma_kernel<<<NEDGES / TE, 256, 0, stream>>>(
        z1b, z2b, efb, esrc, edst,
        B2c + (size_t)l * 256 * 32, aggH);
    upd_mfma_kernel<<<NATOMS / 64, 512, 0, stream>>>(
        h, hb, aggH, degf,
        uW1ft + (size_t)l * 256 * 384, ub1 + (size_t)l * 256,
        b2u + (size_t)l * 256,
        uW2t + (size_t)l * 128 * 256, ub2 + (size_t)l * 128,
        (l < NLAYERS - 1) ? 1 : 0,
        mb1 + (size_t)ln * 256,
        W1at + (size_t)ln * 256 * 128, W1bt + (size_t)ln * 256 * 128,
        z1b, z2b);
  }

  readout_sum_kernel<<<NATOMS / 128, 128, 0, stream>>>(h, batch, gsum, gcnt);
  readout_mlp_kernel<<<1, 256, 0, stream>>>(gsum, gcnt, rW1, rb1, rW2, rb2,
                                            (float*)d_out);
}